// Round 9
// baseline (546.327 us; speedup 1.0000x reference)
//
#include <hip/hip_runtime.h>

namespace {

constexpr int Dn   = 128;
constexpr int DIN  = 512;
constexpr int Hn   = 8;
constexpr int Mn   = 128;
constexpr int DFF  = 512;
constexpr int Gn   = 2;     // batches per block (attention sequential per batch)
constexpr float ATT_SCALE = 0.25f;
constexpr float INV_SQRT2 = 0.70710678118654752440f;

__device__ __forceinline__ unsigned pk_bf16(float lo, float hi) {
    unsigned r;
    asm volatile("v_cvt_pk_bf16_f32 %0, %1, %2" : "=v"(r) : "v"(lo), "v"(hi));
    return r;
}
__device__ __forceinline__ float lo16(unsigned u) { return __uint_as_float(u << 16); }
__device__ __forceinline__ float hi16(unsigned u) { return __uint_as_float(u & 0xffff0000u); }

// dot of a 128-float global row with a 128-float LDS vector (broadcast v)
__device__ __forceinline__ float dot128(const float* __restrict__ wrow,
                                        const float* __restrict__ v)
{
    const float4* w4 = (const float4*)wrow;
    const float4* v4 = (const float4*)v;
    float acc = 0.f;
#pragma unroll
    for (int j = 0; j < 32; ++j) {
        float4 a = w4[j], b = v4[j];
        acc += a.x*b.x + a.y*b.y + a.z*b.z + a.w*b.w;
    }
    return acc;
}

// LayerNorm, 64 threads per row (one wave). In-place safe.
template <int NCOL>
__device__ __forceinline__ void ln_row64(const float* __restrict__ src,
                                         float* __restrict__ dst,
                                         const float* __restrict__ gw,
                                         const float* __restrict__ gb,
                                         const float* __restrict__ resid,
                                         int sub)
{
    constexpr int E = NCOL / 64;
    float v0[E]; float sm = 0.f;
#pragma unroll
    for (int i = 0; i < E; ++i) { v0[i] = src[sub*E + i]; sm += v0[i]; }
#pragma unroll
    for (int m = 32; m >= 1; m >>= 1) sm += __shfl_xor(sm, m);
    float mean = sm * (1.f / (float)NCOL);
    float vs = 0.f;
#pragma unroll
    for (int i = 0; i < E; ++i) { float d0 = v0[i] - mean; vs += d0*d0; }
#pragma unroll
    for (int m = 32; m >= 1; m >>= 1) vs += __shfl_xor(vs, m);
    float rstd = rsqrtf(vs * (1.f / (float)NCOL) + 1e-5f);
#pragma unroll
    for (int i = 0; i < E; ++i) {
        int d = sub*E + i;
        float r = (v0[i] - mean) * rstd * gw[d] + gb[d];
        dst[d] = resid ? (r + resid[d]) : r;
    }
}

// NOTE: min-waves-per-EU >= 3 makes the register allocator spill the attention
// accumulators to scratch (r3: 64 VGPR/267MB, r7: 84 VGPR/122MB writes).
// Keep (256,2); occupancy comes from LDS (~45.7KB -> 3 blocks/CU) and grid
// granularity (Gn=2 -> 2048 blocks = 8/CU packs 3-resident as 3+3+2).
__global__ __launch_bounds__(256, 2)
void fused_block(const float* __restrict__ x,
                 const float* __restrict__ W_in,
                 const float* __restrict__ b_in,
                 const float* __restrict__ pos,
                 const float* __restrict__ mask,
                 const float* __restrict__ mem,
                 const float* __restrict__ ln1_w, const float* __restrict__ ln1_b,
                 const float* __restrict__ W_qkv, const float* __restrict__ b_qkv,
                 const float* __restrict__ W_out, const float* __restrict__ b_out,
                 const float* __restrict__ ln2_w, const float* __restrict__ ln2_b,
                 const float* __restrict__ ln3_w, const float* __restrict__ ln3_b,
                 const float* __restrict__ W_ff1, const float* __restrict__ b_ff1,
                 const float* __restrict__ ln4_w, const float* __restrict__ ln4_b,
                 const float* __restrict__ W_ff2, const float* __restrict__ b_ff2,
                 const float* __restrict__ ln5_w, const float* __restrict__ ln5_b,
                 const float* __restrict__ W_head, const float* __restrict__ b_head,
                 float* __restrict__ out)
{
    const int t    = threadIdx.x;
    const int b0   = blockIdx.x * Gn;
    const int lane = t & 63;
    const int wv   = t >> 6;

    // bf16 tile (32 KB), chunk-XOR swizzled; tail reuse: x / f1 / hh (float view)
    __shared__ __align__(16) unsigned short s16[Mn * Dn];
    __shared__ __align__(16) float s_A[Hn * Dn];     // Aq' fp32 [h][j], 4 KB
    // s_sc: q (alias) -> dots[128][12] (8 dots + rstd) -> qw in place -> ctxn[8][128] -> tail tmp
    __shared__ __align__(16) float s_sc[Mn * 12];
    __shared__ __align__(16) float s_lnq[Dn];
    __shared__ __align__(16) float s_qin[Gn][Dn];
    __shared__ __align__(16) float s_qo[Gn][Dn];
    __shared__ float s_s2c[Hn], s_s0[Hn], s_den[Hn], s_p0[Hn];

    float*  s16f  = (float*)s16;     // 8192 floats
    float*  s_q   = s_sc;            // alias: dead before Pass A writes dots

    //=== P0: stage x [2][512] into tile region ============================
    {
        const float4* src = (const float4*)(x + (size_t)b0 * DIN);
        ((float4*)s16f)[t] = src[t];          // 256 float4 = 1024 floats
    }
    __syncthreads();

    //=== P1: q_in = x @ W_in^T + b_in + pos (1 out/thread, K=512) =========
    {
        int d = t & 127, g = t >> 7;
        float acc = 0.f;
        const float4* w4 = (const float4*)(W_in + (size_t)d * DIN);
        const float4* x4 = (const float4*)(s16f + g*DIN);
#pragma unroll 8
        for (int j = 0; j < DIN/4; ++j) {
            float4 a = w4[j], b = x4[j];
            acc += a.x*b.x + a.y*b.y + a.z*b.z + a.w*b.w;
        }
        s_qin[g][d] = acc + b_in[d] + pos[(size_t)(b0+g)*Dn + d];
    }
    __syncthreads();

    //=== Attention: per batch ============================================
    for (int g = 0; g < Gn; ++g) {
        // S: stage tile as bf16, chunk-swizzled; wave0: lnq; waves 2-3: q
        {
            const float4* src = (const float4*)(mem + (size_t)(b0+g) * Mn * Dn);
#pragma unroll
            for (int i = 0; i < 16; ++i) {
                int fid = t + 256*i;
                float4 v = src[fid];
                int r = fid >> 5, k = fid & 31;
                int c = k >> 1, half = k & 1;
                unsigned u0 = pk_bf16(v.x, v.y), u1 = pk_bf16(v.z, v.w);
                *(uint2*)&s16[r*128 + ((c ^ (r & 7)) << 3) + half*4] = make_uint2(u0, u1);
            }
        }
        if (t < 64) {
            ln_row64<Dn>(&s_qin[g][0], s_lnq, ln1_w, ln1_b, nullptr, t);
        } else if (t >= 128) {
            int dd = t - 128;
            s_q[dd] = dot128(W_qkv + (size_t)dd*Dn, &s_qin[g][0]) + b_qkv[dd];
        }
        __syncthreads();

        // Aq: A' fp32 [h][j] (s1-folded) + per-head scalars s2c/s0
        {
            int h = t >> 5, js = t & 31;
            float aq[4] = {0,0,0,0};
            float ch = 0.f;
#pragma unroll
            for (int d0 = 0; d0 < 16; ++d0) {
                float qv = s_q[h*16 + d0];
                float4 w = ((const float4*)(W_qkv + (size_t)(Dn + h*16 + d0)*Dn))[js];
                aq[0] = fmaf(qv, w.x, aq[0]); aq[1] = fmaf(qv, w.y, aq[1]);
                aq[2] = fmaf(qv, w.z, aq[2]); aq[3] = fmaf(qv, w.w, aq[3]);
                ch = fmaf(qv, b_qkv[Dn + h*16 + d0], ch);
            }
            ch *= ATT_SCALE;
            float s1p = 0.f, s2p = 0.f, s0p = 0.f;
            float aqw[4];
#pragma unroll
            for (int c = 0; c < 4; ++c) {
                int j = js*4 + c;
                float a = ATT_SCALE * aq[c];
                aqw[c] = a * ln1_w[j];
                s1p += aqw[c];
                s2p = fmaf(a, ln1_b[j], s2p);
                s0p = fmaf(a, s_lnq[j], s0p);
            }
#pragma unroll
            for (int m = 16; m >= 1; m >>= 1) {
                s1p += __shfl_xor(s1p, m, 32);
                s2p += __shfl_xor(s2p, m, 32);
                s0p += __shfl_xor(s0p, m, 32);
            }
            float sub = s1p * (1.f/128.f);
            *(float4*)&s_A[h*Dn + 4*js] =
                make_float4(aqw[0]-sub, aqw[1]-sub, aqw[2]-sub, aqw[3]-sub);
            if (js == 0) { s_s2c[h] = s2p + ch; s_s0[h] = s0p + ch; }
        }
        __syncthreads();

        // A: raw head-dots + row stats (2 lanes/row; bf16 tile, fp32 A)
        {
            int r = t >> 1, hf = t & 1;
            float d8[8] = {0,0,0,0,0,0,0,0};
            float sum = 0.f, ssq = 0.f;
#pragma unroll
            for (int kk = 0; kk < 8; ++kk) {
                int c = hf*8 + kk;
                uint4 tv = *(const uint4*)&s16[r*128 + ((c ^ (r & 7)) << 3)];
                float vv[8];
                vv[0] = lo16(tv.x); vv[1] = hi16(tv.x);
                vv[2] = lo16(tv.y); vv[3] = hi16(tv.y);
                vv[4] = lo16(tv.z); vv[5] = hi16(tv.z);
                vv[6] = lo16(tv.w); vv[7] = hi16(tv.w);
#pragma unroll
                for (int q = 0; q < 8; ++q) { sum += vv[q]; ssq = fmaf(vv[q], vv[q], ssq); }
#pragma unroll
                for (int h = 0; h < 8; ++h) {
                    const float4* ap = (const float4*)&s_A[h*Dn + c*8];
                    float4 a0 = ap[0], a1 = ap[1];
                    d8[h] = fmaf(a0.x, vv[0], d8[h]); d8[h] = fmaf(a0.y, vv[1], d8[h]);
                    d8[h] = fmaf(a0.z, vv[2], d8[h]); d8[h] = fmaf(a0.w, vv[3], d8[h]);
                    d8[h] = fmaf(a1.x, vv[4], d8[h]); d8[h] = fmaf(a1.y, vv[5], d8[h]);
                    d8[h] = fmaf(a1.z, vv[6], d8[h]); d8[h] = fmaf(a1.w, vv[7], d8[h]);
                }
            }
            sum += __shfl_xor(sum, 1);
            ssq += __shfl_xor(ssq, 1);
#pragma unroll
            for (int h = 0; h < 8; ++h) d8[h] += __shfl_xor(d8[h], 1);
            if (hf == 0) {
                float mean = sum * (1.f/128.f);
                float var  = fmaf(-mean, mean, ssq * (1.f/128.f));
                float rstd = rsqrtf(var + 1e-5f);
                *(float4*)&s_sc[r*12]     = make_float4(d8[0], d8[1], d8[2], d8[3]);
                *(float4*)&s_sc[r*12 + 4] = make_float4(d8[4], d8[5], d8[6], d8[7]);
                s_sc[r*12 + 8] = rstd;
            }
        }
        __syncthreads();

        // SM: one-shot softmax; wave w -> heads 2w,2w+1; lane l -> rows 2l,2l+1.
        // qw overwrites the dots slots in place (each lane rewrites only its own).
        {
            int w = wv, l = lane;
            int h0 = 2*w, h1 = h0 + 1;
            int r0 = 2*l, r1 = r0 + 1;
            float2 da = *(const float2*)&s_sc[r0*12 + h0];
            float2 db = *(const float2*)&s_sc[r1*12 + h0];
            float rs0 = s_sc[r0*12 + 8], rs1 = s_sc[r1*12 + 8];
            float2 mk = *(const float2*)&mask[(size_t)(b0+g)*Mn + r0];
            float sc00 = fmaf(rs0, da.x, s_s2c[h0]) + mk.x;
            float sc01 = fmaf(rs0, da.y, s_s2c[h1]) + mk.x;
            float sc10 = fmaf(rs1, db.x, s_s2c[h0]) + mk.y;
            float sc11 = fmaf(rs1, db.y, s_s2c[h1]) + mk.y;
            float mx0 = fmaxf(sc00, sc10), mx1 = fmaxf(sc01, sc11);
#pragma unroll
            for (int m = 1; m < 64; m <<= 1) {
                mx0 = fmaxf(mx0, __shfl_xor(mx0, m));
                mx1 = fmaxf(mx1, __shfl_xor(mx1, m));
            }
            mx0 = fmaxf(mx0, s_s0[h0]);
            mx1 = fmaxf(mx1, s_s0[h1]);
            float e00 = __expf(sc00 - mx0), e10 = __expf(sc10 - mx0);
            float e01 = __expf(sc01 - mx1), e11 = __expf(sc11 - mx1);
            float ds0 = e00 + e10, ds1 = e01 + e11;
#pragma unroll
            for (int m = 1; m < 64; m <<= 1) {
                ds0 += __shfl_xor(ds0, m);
                ds1 += __shfl_xor(ds1, m);
            }
            float p00 = __expf(s_s0[h0] - mx0), p01 = __expf(s_s0[h1] - mx1);
            *(float2*)&s_sc[r0*12 + h0] = make_float2(e00*rs0, e01*rs0);
            *(float2*)&s_sc[r1*12 + h0] = make_float2(e10*rs1, e11*rs1);
            if (l == 0) {
                s_den[h0] = ds0 + p00; s_p0[h0] = p00;
                s_den[h1] = ds1 + p01; s_p0[h1] = p01;
            }
        }
        __syncthreads();

        // C: ctx (wave = head pair; quarter = 32 rows; lane chunk = 8 cols)
        float cx0[8], cx1[8], cS0, cS1;
        {
            int w = wv, l = lane;
            int qtr = l >> 4, c = l & 15;
#pragma unroll
            for (int q = 0; q < 8; ++q) { cx0[q] = 0.f; cx1[q] = 0.f; }
#pragma unroll 4
            for (int rr = 0; rr < 32; ++rr) {
                int r = qtr*32 + rr;
                uint4 tv = *(const uint4*)&s16[r*128 + ((c ^ (r & 7)) << 3)];
                float2 qv = *(const float2*)&s_sc[r*12 + 2*w];
                float v0 = lo16(tv.x), v1 = hi16(tv.x);
                float v2 = lo16(tv.y), v3 = hi16(tv.y);
                float v4 = lo16(tv.z), v5 = hi16(tv.z);
                float v6 = lo16(tv.w), v7 = hi16(tv.w);
                cx0[0]=fmaf(qv.x,v0,cx0[0]); cx1[0]=fmaf(qv.y,v0,cx1[0]);
                cx0[1]=fmaf(qv.x,v1,cx0[1]); cx1[1]=fmaf(qv.y,v1,cx1[1]);
                cx0[2]=fmaf(qv.x,v2,cx0[2]); cx1[2]=fmaf(qv.y,v2,cx1[2]);
                cx0[3]=fmaf(qv.x,v3,cx0[3]); cx1[3]=fmaf(qv.y,v3,cx1[3]);
                cx0[4]=fmaf(qv.x,v4,cx0[4]); cx1[4]=fmaf(qv.y,v4,cx1[4]);
                cx0[5]=fmaf(qv.x,v5,cx0[5]); cx1[5]=fmaf(qv.y,v5,cx1[5]);
                cx0[6]=fmaf(qv.x,v6,cx0[6]); cx1[6]=fmaf(qv.y,v6,cx1[6]);
                cx0[7]=fmaf(qv.x,v7,cx0[7]); cx1[7]=fmaf(qv.y,v7,cx1[7]);
            }
            // combine the 4 row-quarters
#pragma unroll
            for (int q = 0; q < 8; ++q) {
                cx0[q] += __shfl_xor(cx0[q], 16);
                cx0[q] += __shfl_xor(cx0[q], 32);
                cx1[q] += __shfl_xor(cx1[q], 16);
                cx1[q] += __shfl_xor(cx1[q], 32);
            }
            // cS = sum_j ctx_raw / 128  (butterfly over the 16 chunks)
            float sA = ((cx0[0]+cx0[1])+(cx0[2]+cx0[3])) + ((cx0[4]+cx0[5])+(cx0[6]+cx0[7]));
            float sB = ((cx1[0]+cx1[1])+(cx1[2]+cx1[3])) + ((cx1[4]+cx1[5])+(cx1[6]+cx1[7]));
#pragma unroll
            for (int m = 1; m < 16; m <<= 1) {
                sA += __shfl_xor(sA, m);
                sB += __shfl_xor(sB, m);
            }
            cS0 = sA * (1.f/128.f);
            cS1 = sB * (1.f/128.f);
        }
        __syncthreads();   // all qw reads done before ctxn overwrites s_sc

        // D: verified fold -> ctxn[8][128] into s_sc (lanes 0..15 of each wave)
        if (lane < 16) {
            int c = lane;
            int h0 = 2*wv, h1 = h0 + 1;
            float den0 = s_den[h0], p0a = s_p0[h0], sP0 = den0 - p0a, inv0 = 1.f/den0;
            float den1 = s_den[h1], p0b = s_p0[h1], sP1 = den1 - p0b, inv1 = 1.f/den1;
#pragma unroll
            for (int q = 0; q < 2; ++q) {
                int j0 = c*8 + q*4;
                float4 lq = *(const float4*)&s_lnq[j0];
                float4 lw = *(const float4*)&ln1_w[j0];
                float4 lb = *(const float4*)&ln1_b[j0];
                float4 o0, o1;
                o0.x = (p0a*lq.x + lw.x*(cx0[q*4+0]-cS0) + lb.x*sP0) * inv0;
                o0.y = (p0a*lq.y + lw.y*(cx0[q*4+1]-cS0) + lb.y*sP0) * inv0;
                o0.z = (p0a*lq.z + lw.z*(cx0[q*4+2]-cS0) + lb.z*sP0) * inv0;
                o0.w = (p0a*lq.w + lw.w*(cx0[q*4+3]-cS0) + lb.w*sP0) * inv0;
                o1.x = (p0b*lq.x + lw.x*(cx1[q*4+0]-cS1) + lb.x*sP1) * inv1;
                o1.y = (p0b*lq.y + lw.y*(cx1[q*4+1]-cS1) + lb.y*sP1) * inv1;
                o1.z = (p0b*lq.z + lw.z*(cx1[q*4+2]-cS1) + lb.z*sP1) * inv1;
                o1.w = (p0b*lq.w + lw.w*(cx1[q*4+3]-cS1) + lb.w*sP1) * inv1;
                *(float4*)&s_sc[h0*128 + j0] = o0;
                *(float4*)&s_sc[h1*128 + j0] = o1;
            }
        }
        __syncthreads();

        // O: o = Wv @ ctxn + bv
        if (t < 128) {
            int h = t >> 4;
            s_qo[g][t] = dot128(W_qkv + (size_t)(2*Dn + t)*Dn, &s_sc[h*128])
                       + b_qkv[2*Dn + t];
        }
        __syncthreads();
    }

    //=== Tail (Gn=2) ======================================================
    // P6a: t1 = o @ W_out^T + b_out  (1 out/thread)
    {
        int d = t & 127, g = t >> 7;
        s_sc[g*128 + d] = dot128(W_out + (size_t)d * Dn, &s_qo[g][0]) + b_out[d];
    }
    __syncthreads();

    // P6b: h = LN(t1, ln2) + q_in -> s16f[2048 + g*128]  (tile region, dead)
    if (wv < 2)
        ln_row64<Dn>(&s_sc[wv*128], &s16f[2048 + wv*128], ln2_w, ln2_b,
                     &s_qin[wv][0], lane);
    __syncthreads();
    // P6c: ln3h = LN(h, ln3) -> s_qin
    if (wv < 2)
        ln_row64<Dn>(&s16f[2048 + wv*128], &s_qin[wv][0], ln3_w, ln3_b, nullptr, lane);
    __syncthreads();

    // P6d: f1 = gelu(ln3h @ W_ff1^T + b_ff1) -> s16f[g*512 + e]
    {
        int e0 = t, e1 = t + 256;
        const float4* wa = (const float4*)(W_ff1 + (size_t)e0 * Dn);
        const float4* wb = (const float4*)(W_ff1 + (size_t)e1 * Dn);
        float acc0[2] = {0,0}, acc1[2] = {0,0};
#pragma unroll 4
        for (int j = 0; j < 32; ++j) {
            float4 a = wa[j], b = wb[j];
#pragma unroll
            for (int g2 = 0; g2 < 2; ++g2) {
                float4 v = *(const float4*)&s_qin[g2][j*4];
                acc0[g2] = fmaf(a.x,v.x,acc0[g2]); acc0[g2] = fmaf(a.y,v.y,acc0[g2]);
                acc0[g2] = fmaf(a.z,v.z,acc0[g2]); acc0[g2] = fmaf(a.w,v.w,acc0[g2]);
                acc1[g2] = fmaf(b.x,v.x,acc1[g2]); acc1[g2] = fmaf(b.y,v.y,acc1[g2]);
                acc1[g2] = fmaf(b.z,v.z,acc1[g2]); acc1[g2] = fmaf(b.w,v.w,acc1[g2]);
            }
        }
#pragma unroll
        for (int g2 = 0; g2 < 2; ++g2) {
            float v0 = acc0[g2] + b_ff1[e0];
            float v1 = acc1[g2] + b_ff1[e1];
            s16f[g2*512 + e0] = 0.5f * v0 * (1.f + erff(v0 * INV_SQRT2));
            s16f[g2*512 + e1] = 0.5f * v1 * (1.f + erff(v1 * INV_SQRT2));
        }
    }
    __syncthreads();

    // P6e: LN(f1, ln4) in place
    if (wv < 2)
        ln_row64<DFF>(&s16f[wv*512], &s16f[wv*512], ln4_w, ln4_b, nullptr, lane);
    __syncthreads();

    // P6f: f2 = f1 @ W_ff2^T + b_ff2 + h -> s_sc  (1 out/thread, K=512)
    {
        int d = t & 127, g = t >> 7;
        const float4* w4 = (const float4*)(W_ff2 + (size_t)d * DFF);
        const float4* v4 = (const float4*)(s16f + g*DFF);
        float acc = 0.f;
#pragma unroll 8
        for (int j = 0; j < DFF/4; ++j) {
            float4 a = w4[j], v = v4[j];
            acc += a.x*v.x + a.y*v.y + a.z*v.z + a.w*v.w;
        }
        s_sc[g*128 + d] = acc + b_ff2[d] + s16f[2048 + g*128 + d];
    }
    __syncthreads();

    // P6g: h2 = LN(ln5) -> s_qin
    if (wv < 2)
        ln_row64<Dn>(&s_sc[wv*128], &s_qin[wv][0], ln5_w, ln5_b, nullptr, lane);
    __syncthreads();

    // P6h: out = h2 @ W_head^T + b_head
    {
        int e0 = t, e1 = t + 256;
        const float4* wa = (const float4*)(W_head + (size_t)e0 * Dn);
        const float4* wb = (const float4*)(W_head + (size_t)e1 * Dn);
        float acc0[2] = {0,0}, acc1[2] = {0,0};
#pragma unroll 4
        for (int j = 0; j < 32; ++j) {
            float4 a = wa[j], b = wb[j];
#pragma unroll
            for (int g2 = 0; g2 < 2; ++g2) {
                float4 v = *(const float4*)&s_qin[g2][j*4];
                acc0[g2] = fmaf(a.x,v.x,acc0[g2]); acc0[g2] = fmaf(a.y,v.y,acc0[g2]);
                acc0[g2] = fmaf(a.z,v.z,acc0[g2]); acc0[g2] = fmaf(a.w,v.w,acc0[g2]);
                acc1[g2] = fmaf(b.x,v.x,acc1[g2]); acc1[g2] = fmaf(b.y,v.y,acc1[g2]);
                acc1[g2] = fmaf(b.z,v.z,acc1[g2]); acc1[g2] = fmaf(b.w,v.w,acc1[g2]);
            }
        }
#pragma unroll
        for (int g2 = 0; g2 < 2; ++g2) {
            out[(size_t)(b0+g2)*DIN + e0] = acc0[g2] + b_head[e0];
            out[(size_t)(b0+g2)*DIN + e1] = acc1[g2] + b_head[e1];
        }
    }
}

} // namespace

extern "C" void kernel_launch(void* const* d_in, const int* in_sizes, int n_in,
                              void* d_out, int out_size, void* d_ws, size_t ws_size,
                              hipStream_t stream)
{
    const float* x      = (const float*)d_in[0];
    const float* W_in   = (const float*)d_in[1];
    const float* b_in   = (const float*)d_in[2];
    const float* pos    = (const float*)d_in[3];
    const float* mask   = (const float*)d_in[4];
    const float* mem    = (const float*)d_in[5];
    const float* ln1_w  = (const float*)d_in[6];
    const float* ln1_b  = (const float*)d_in[7];
    const float* W_qkv  = (const float*)d_in[8];
    const float* b_qkv  = (const float*)d_in[9];
    const float* W_out  = (const float*)d_in[10];
    const float* b_out  = (const float*)d_in[11];
    const float* ln2_w  = (const float*)d_in[12];
    const float* ln2_b  = (const float*)d_in[13];
    const float* ln3_w  = (const float*)d_in[14];
    const float* ln3_b  = (const float*)d_in[15];
    const float* W_ff1  = (const float*)d_in[16];
    const float* b_ff1  = (const float*)d_in[17];
    const float* ln4_w  = (const float*)d_in[18];
    const float* ln4_b  = (const float*)d_in[19];
    const float* W_ff2  = (const float*)d_in[20];
    const float* b_ff2  = (const float*)d_in[21];
    const float* ln5_w  = (const float*)d_in[22];
    const float* ln5_b  = (const float*)d_in[23];
    const float* W_head = (const float*)d_in[24];
    const float* b_head = (const float*)d_in[25];

    const int B = in_sizes[0] / DIN;   // 4096
    fused_block<<<dim3(B / Gn), dim3(256), 0, stream>>>(
        x, W_in, b_in, pos, mask, mem,
        ln1_w, ln1_b, W_qkv, b_qkv, W_out, b_out,
        ln2_w, ln2_b, ln3_w, ln3_b,
        W_ff1, b_ff1, ln4_w, ln4_b, W_ff2, b_ff2,
        ln5_w, ln5_b, W_head, b_head,
        (float*)d_out);
}

// Round 10
// 328.804 us; speedup vs baseline: 1.6616x; 1.6616x over previous
//
#include <hip/hip_runtime.h>

namespace {

constexpr int Dn   = 128;
constexpr int DIN  = 512;
constexpr int Hn   = 8;
constexpr int Mn   = 128;
constexpr int DFF  = 512;
constexpr float ATT_SCALE = 0.25f;
constexpr float INV_SQRT2 = 0.70710678118654752440f;

__device__ __forceinline__ unsigned pk_bf16(float lo, float hi) {
    unsigned r;
    asm volatile("v_cvt_pk_bf16_f32 %0, %1, %2" : "=v"(r) : "v"(lo), "v"(hi));
    return r;
}
__device__ __forceinline__ float lo16(unsigned u) { return __uint_as_float(u << 16); }
__device__ __forceinline__ float hi16(unsigned u) { return __uint_as_float(u & 0xffff0000u); }

__device__ __forceinline__ float dot128(const float* __restrict__ wrow,
                                        const float* __restrict__ v)
{
    const float4* w4 = (const float4*)wrow;
    const float4* v4 = (const float4*)v;
    float acc = 0.f;
#pragma unroll
    for (int j = 0; j < 32; ++j) {
        float4 a = w4[j], b = v4[j];
        acc += a.x*b.x + a.y*b.y + a.z*b.z + a.w*b.w;
    }
    return acc;
}

template <int NCOL>
__device__ __forceinline__ void ln_row64(const float* __restrict__ src,
                                         float* __restrict__ dst,
                                         const float* __restrict__ gw,
                                         const float* __restrict__ gb,
                                         const float* __restrict__ resid,
                                         int sub)
{
    constexpr int E = NCOL / 64;
    float v0[E]; float sm = 0.f;
#pragma unroll
    for (int i = 0; i < E; ++i) { v0[i] = src[sub*E + i]; sm += v0[i]; }
#pragma unroll
    for (int m = 32; m >= 1; m >>= 1) sm += __shfl_xor(sm, m);
    float mean = sm * (1.f / (float)NCOL);
    float vs = 0.f;
#pragma unroll
    for (int i = 0; i < E; ++i) { float d0 = v0[i] - mean; vs += d0*d0; }
#pragma unroll
    for (int m = 32; m >= 1; m >>= 1) vs += __shfl_xor(vs, m);
    float rstd = rsqrtf(vs * (1.f / (float)NCOL) + 1e-5f);
#pragma unroll
    for (int i = 0; i < E; ++i) {
        int d = sub*E + i;
        float r = (v0[i] - mean) * rstd * gw[d] + gb[d];
        dst[d] = resid ? (r + resid[d]) : r;
    }
}

//======================= Kernel A: q_in projection =======================
// 8 batches/block, weight-reusing. q_in = x @ W_in^T + b_in + pos -> ws.
__global__ __launch_bounds__(256, 2)
void k_qin(const float* __restrict__ x, const float* __restrict__ W_in,
           const float* __restrict__ b_in, const float* __restrict__ pos,
           float* __restrict__ q_in)
{
    const int t  = threadIdx.x;
    const int b0 = blockIdx.x * 8;
    __shared__ __align__(16) float s_x[8 * DIN];
    {
        const float4* src = (const float4*)(x + (size_t)b0 * DIN);
        float4* dst = (float4*)s_x;
#pragma unroll
        for (int i = 0; i < 4; ++i) dst[t + 256*i] = src[t + 256*i];
    }
    __syncthreads();
    {
        int d = t & 127, gq = t >> 7;
        const float4* w4 = (const float4*)(W_in + (size_t)d * DIN);
        float acc[4] = {0,0,0,0};
        for (int j = 0; j < DIN/4; ++j) {
            float4 a = w4[j];
#pragma unroll
            for (int g = 0; g < 4; ++g) {
                float4 xv = ((const float4*)s_x)[(gq*4 + g)*(DIN/4) + j];
                acc[g] = fmaf(a.x, xv.x, acc[g]); acc[g] = fmaf(a.y, xv.y, acc[g]);
                acc[g] = fmaf(a.z, xv.z, acc[g]); acc[g] = fmaf(a.w, xv.w, acc[g]);
            }
        }
#pragma unroll
        for (int g = 0; g < 4; ++g) {
            int gb = b0 + gq*4 + g;
            q_in[(size_t)gb*Dn + d] = acc[g] + b_in[d] + pos[(size_t)gb*Dn + d];
        }
    }
}

//======================= Kernel B: attention (1 batch/block) ==============
__global__ __launch_bounds__(256, 2)
void k_attn(const float* __restrict__ q_in,
            const float* __restrict__ mask,
            const float* __restrict__ mem,
            const float* __restrict__ ln1_w, const float* __restrict__ ln1_b,
            const float* __restrict__ W_qkv, const float* __restrict__ b_qkv,
            float* __restrict__ o_ws)
{
    const int t    = threadIdx.x;
    const int lane = t & 63;
    const int wv   = t >> 6;
    const int b    = blockIdx.x;

    __shared__ __align__(16) unsigned short s16[Mn * Dn];   // bf16 tile, swizzled
    __shared__ __align__(16) float s_A[Hn * Dn];            // Aq' fp32 [h][j]
    __shared__ __align__(16) float s_sc[Mn * 12];           // q -> dots+rstd -> qw -> ctxn
    __shared__ __align__(16) float s_lnq[Dn];
    __shared__ __align__(16) float s_qi[Dn];
    __shared__ float s_s2c[Hn], s_s0[Hn], s_den[Hn], s_p0[Hn];

    float* s_q = s_sc;   // alias: dead before Pass A writes dots

    if (t < 32) ((float4*)s_qi)[t] = ((const float4*)(q_in + (size_t)b*Dn))[t];
    __syncthreads();

    // S: stage tile bf16 chunk-swizzled; wave0 lnq; waves 2-3 q
    {
        const float4* src = (const float4*)(mem + (size_t)b * Mn * Dn);
#pragma unroll
        for (int i = 0; i < 16; ++i) {
            int fid = t + 256*i;
            float4 v = src[fid];
            int r = fid >> 5, k = fid & 31;
            int c = k >> 1, half = k & 1;
            unsigned u0 = pk_bf16(v.x, v.y), u1 = pk_bf16(v.z, v.w);
            *(uint2*)&s16[r*128 + ((c ^ (r & 7)) << 3) + half*4] = make_uint2(u0, u1);
        }
    }
    if (t < 64) {
        ln_row64<Dn>(s_qi, s_lnq, ln1_w, ln1_b, nullptr, t);
    } else if (t >= 128) {
        int dd = t - 128;
        s_q[dd] = dot128(W_qkv + (size_t)dd*Dn, s_qi) + b_qkv[dd];
    }
    __syncthreads();

    // Aq: A' fp32 [h][j] (s1-folded) + per-head scalars s2c/s0
    {
        int h = t >> 5, js = t & 31;
        float aq[4] = {0,0,0,0};
        float ch = 0.f;
#pragma unroll
        for (int d0 = 0; d0 < 16; ++d0) {
            float qv = s_q[h*16 + d0];
            float4 w = ((const float4*)(W_qkv + (size_t)(Dn + h*16 + d0)*Dn))[js];
            aq[0] = fmaf(qv, w.x, aq[0]); aq[1] = fmaf(qv, w.y, aq[1]);
            aq[2] = fmaf(qv, w.z, aq[2]); aq[3] = fmaf(qv, w.w, aq[3]);
            ch = fmaf(qv, b_qkv[Dn + h*16 + d0], ch);
        }
        ch *= ATT_SCALE;
        float s1p = 0.f, s2p = 0.f, s0p = 0.f;
        float aqw[4];
#pragma unroll
        for (int c = 0; c < 4; ++c) {
            int j = js*4 + c;
            float a = ATT_SCALE * aq[c];
            aqw[c] = a * ln1_w[j];
            s1p += aqw[c];
            s2p = fmaf(a, ln1_b[j], s2p);
            s0p = fmaf(a, s_lnq[j], s0p);
        }
#pragma unroll
        for (int m = 16; m >= 1; m >>= 1) {
            s1p += __shfl_xor(s1p, m, 32);
            s2p += __shfl_xor(s2p, m, 32);
            s0p += __shfl_xor(s0p, m, 32);
        }
        float sub = s1p * (1.f/128.f);
        *(float4*)&s_A[h*Dn + 4*js] =
            make_float4(aqw[0]-sub, aqw[1]-sub, aqw[2]-sub, aqw[3]-sub);
        if (js == 0) { s_s2c[h] = s2p + ch; s_s0[h] = s0p + ch; }
    }
    __syncthreads();

    // A: raw head-dots + row stats (2 lanes/row; bf16 tile, fp32 A)
    {
        int r = t >> 1, hf = t & 1;
        float d8[8] = {0,0,0,0,0,0,0,0};
        float sum = 0.f, ssq = 0.f;
#pragma unroll
        for (int kk = 0; kk < 8; ++kk) {
            int c = hf*8 + kk;
            uint4 tv = *(const uint4*)&s16[r*128 + ((c ^ (r & 7)) << 3)];
            float vv[8];
            vv[0] = lo16(tv.x); vv[1] = hi16(tv.x);
            vv[2] = lo16(tv.y); vv[3] = hi16(tv.y);
            vv[4] = lo16(tv.z); vv[5] = hi16(tv.z);
            vv[6] = lo16(tv.w); vv[7] = hi16(tv.w);
#pragma unroll
            for (int q = 0; q < 8; ++q) { sum += vv[q]; ssq = fmaf(vv[q], vv[q], ssq); }
#pragma unroll
            for (int h = 0; h < 8; ++h) {
                const float4* ap = (const float4*)&s_A[h*Dn + c*8];
                float4 a0 = ap[0], a1 = ap[1];
                d8[h] = fmaf(a0.x, vv[0], d8[h]); d8[h] = fmaf(a0.y, vv[1], d8[h]);
                d8[h] = fmaf(a0.z, vv[2], d8[h]); d8[h] = fmaf(a0.w, vv[3], d8[h]);
                d8[h] = fmaf(a1.x, vv[4], d8[h]); d8[h] = fmaf(a1.y, vv[5], d8[h]);
                d8[h] = fmaf(a1.z, vv[6], d8[h]); d8[h] = fmaf(a1.w, vv[7], d8[h]);
            }
        }
        sum += __shfl_xor(sum, 1);
        ssq += __shfl_xor(ssq, 1);
#pragma unroll
        for (int h = 0; h < 8; ++h) d8[h] += __shfl_xor(d8[h], 1);
        if (hf == 0) {
            float mean = sum * (1.f/128.f);
            float var  = fmaf(-mean, mean, ssq * (1.f/128.f));
            float rstd = rsqrtf(var + 1e-5f);
            *(float4*)&s_sc[r*12]     = make_float4(d8[0], d8[1], d8[2], d8[3]);
            *(float4*)&s_sc[r*12 + 4] = make_float4(d8[4], d8[5], d8[6], d8[7]);
            s_sc[r*12 + 8] = rstd;
        }
    }
    __syncthreads();

    // SM: one-shot softmax; wave w -> heads 2w,2w+1; lane l -> rows 2l,2l+1
    {
        int w = wv, l = lane;
        int h0 = 2*w, h1 = h0 + 1;
        int r0 = 2*l, r1 = r0 + 1;
        float2 da = *(const float2*)&s_sc[r0*12 + h0];
        float2 db = *(const float2*)&s_sc[r1*12 + h0];
        float rs0 = s_sc[r0*12 + 8], rs1 = s_sc[r1*12 + 8];
        float2 mk = *(const float2*)&mask[(size_t)b*Mn + r0];
        float sc00 = fmaf(rs0, da.x, s_s2c[h0]) + mk.x;
        float sc01 = fmaf(rs0, da.y, s_s2c[h1]) + mk.x;
        float sc10 = fmaf(rs1, db.x, s_s2c[h0]) + mk.y;
        float sc11 = fmaf(rs1, db.y, s_s2c[h1]) + mk.y;
        float mx0 = fmaxf(sc00, sc10), mx1 = fmaxf(sc01, sc11);
#pragma unroll
        for (int m = 1; m < 64; m <<= 1) {
            mx0 = fmaxf(mx0, __shfl_xor(mx0, m));
            mx1 = fmaxf(mx1, __shfl_xor(mx1, m));
        }
        mx0 = fmaxf(mx0, s_s0[h0]);
        mx1 = fmaxf(mx1, s_s0[h1]);
        float e00 = __expf(sc00 - mx0), e10 = __expf(sc10 - mx0);
        float e01 = __expf(sc01 - mx1), e11 = __expf(sc11 - mx1);
        float ds0 = e00 + e10, ds1 = e01 + e11;
#pragma unroll
        for (int m = 1; m < 64; m <<= 1) {
            ds0 += __shfl_xor(ds0, m);
            ds1 += __shfl_xor(ds1, m);
        }
        float p00 = __expf(s_s0[h0] - mx0), p01 = __expf(s_s0[h1] - mx1);
        *(float2*)&s_sc[r0*12 + h0] = make_float2(e00*rs0, e01*rs0);
        *(float2*)&s_sc[r1*12 + h0] = make_float2(e10*rs1, e11*rs1);
        if (l == 0) {
            s_den[h0] = ds0 + p00; s_p0[h0] = p00;
            s_den[h1] = ds1 + p01; s_p0[h1] = p01;
        }
    }
    __syncthreads();

    // C: ctx (wave = head pair; quarter = 32 rows; lane chunk = 8 cols)
    float cx0[8], cx1[8], cS0, cS1;
    {
        int w = wv, l = lane;
        int qtr = l >> 4, c = l & 15;
#pragma unroll
        for (int q = 0; q < 8; ++q) { cx0[q] = 0.f; cx1[q] = 0.f; }
#pragma unroll 4
        for (int rr = 0; rr < 32; ++rr) {
            int r = qtr*32 + rr;
            uint4 tv = *(const uint4*)&s16[r*128 + ((c ^ (r & 7)) << 3)];
            float2 qv = *(const float2*)&s_sc[r*12 + 2*w];
            float v0 = lo16(tv.x), v1 = hi16(tv.x);
            float v2 = lo16(tv.y), v3 = hi16(tv.y);
            float v4 = lo16(tv.z), v5 = hi16(tv.z);
            float v6 = lo16(tv.w), v7 = hi16(tv.w);
            cx0[0]=fmaf(qv.x,v0,cx0[0]); cx1[0]=fmaf(qv.y,v0,cx1[0]);
            cx0[1]=fmaf(qv.x,v1,cx0[1]); cx1[1]=fmaf(qv.y,v1,cx1[1]);
            cx0[2]=fmaf(qv.x,v2,cx0[2]); cx1[2]=fmaf(qv.y,v2,cx1[2]);
            cx0[3]=fmaf(qv.x,v3,cx0[3]); cx1[3]=fmaf(qv.y,v3,cx1[3]);
            cx0[4]=fmaf(qv.x,v4,cx0[4]); cx1[4]=fmaf(qv.y,v4,cx1[4]);
            cx0[5]=fmaf(qv.x,v5,cx0[5]); cx1[5]=fmaf(qv.y,v5,cx1[5]);
            cx0[6]=fmaf(qv.x,v6,cx0[6]); cx1[6]=fmaf(qv.y,v6,cx1[6]);
            cx0[7]=fmaf(qv.x,v7,cx0[7]); cx1[7]=fmaf(qv.y,v7,cx1[7]);
        }
#pragma unroll
        for (int q = 0; q < 8; ++q) {
            cx0[q] += __shfl_xor(cx0[q], 16);
            cx0[q] += __shfl_xor(cx0[q], 32);
            cx1[q] += __shfl_xor(cx1[q], 16);
            cx1[q] += __shfl_xor(cx1[q], 32);
        }
        float sA = ((cx0[0]+cx0[1])+(cx0[2]+cx0[3])) + ((cx0[4]+cx0[5])+(cx0[6]+cx0[7]));
        float sB = ((cx1[0]+cx1[1])+(cx1[2]+cx1[3])) + ((cx1[4]+cx1[5])+(cx1[6]+cx1[7]));
#pragma unroll
        for (int m = 1; m < 16; m <<= 1) {
            sA += __shfl_xor(sA, m);
            sB += __shfl_xor(sB, m);
        }
        cS0 = sA * (1.f/128.f);
        cS1 = sB * (1.f/128.f);
    }
    __syncthreads();   // qw reads done before ctxn overwrites s_sc

    // D: verified fold -> ctxn[8][128] into s_sc
    if (lane < 16) {
        int c = lane;
        int h0 = 2*wv, h1 = h0 + 1;
        float den0 = s_den[h0], p0a = s_p0[h0], sP0 = den0 - p0a, inv0 = 1.f/den0;
        float den1 = s_den[h1], p0b = s_p0[h1], sP1 = den1 - p0b, inv1 = 1.f/den1;
#pragma unroll
        for (int q = 0; q < 2; ++q) {
            int j0 = c*8 + q*4;
            float4 lq = *(const float4*)&s_lnq[j0];
            float4 lw = *(const float4*)&ln1_w[j0];
            float4 lb = *(const float4*)&ln1_b[j0];
            float4 o0, o1;
            o0.x = (p0a*lq.x + lw.x*(cx0[q*4+0]-cS0) + lb.x*sP0) * inv0;
            o0.y = (p0a*lq.y + lw.y*(cx0[q*4+1]-cS0) + lb.y*sP0) * inv0;
            o0.z = (p0a*lq.z + lw.z*(cx0[q*4+2]-cS0) + lb.z*sP0) * inv0;
            o0.w = (p0a*lq.w + lw.w*(cx0[q*4+3]-cS0) + lb.w*sP0) * inv0;
            o1.x = (p0b*lq.x + lw.x*(cx1[q*4+0]-cS1) + lb.x*sP1) * inv1;
            o1.y = (p0b*lq.y + lw.y*(cx1[q*4+1]-cS1) + lb.y*sP1) * inv1;
            o1.z = (p0b*lq.z + lw.z*(cx1[q*4+2]-cS1) + lb.z*sP1) * inv1;
            o1.w = (p0b*lq.w + lw.w*(cx1[q*4+3]-cS1) + lb.w*sP1) * inv1;
            *(float4*)&s_sc[h0*128 + j0] = o0;
            *(float4*)&s_sc[h1*128 + j0] = o1;
        }
    }
    __syncthreads();

    // O: o = Wv @ ctxn + bv -> ws
    if (t < 128) {
        int h = t >> 4;
        o_ws[(size_t)b*Dn + t] = dot128(W_qkv + (size_t)(2*Dn + t)*Dn, &s_sc[h*128])
                               + b_qkv[2*Dn + t];
    }
}

//======================= Kernel C: MLP tail (4 batches/block) =============
__global__ __launch_bounds__(256, 2)
void k_tail(const float* __restrict__ q_in, const float* __restrict__ o_ws,
            const float* __restrict__ W_out, const float* __restrict__ b_out,
            const float* __restrict__ ln2_w, const float* __restrict__ ln2_b,
            const float* __restrict__ ln3_w, const float* __restrict__ ln3_b,
            const float* __restrict__ W_ff1, const float* __restrict__ b_ff1,
            const float* __restrict__ ln4_w, const float* __restrict__ ln4_b,
            const float* __restrict__ W_ff2, const float* __restrict__ b_ff2,
            const float* __restrict__ ln5_w, const float* __restrict__ ln5_b,
            const float* __restrict__ W_head, const float* __restrict__ b_head,
            float* __restrict__ out)
{
    const int t    = threadIdx.x;
    const int lane = t & 63;
    const int wv   = t >> 6;
    const int b0   = blockIdx.x * 4;

    __shared__ __align__(16) float s_qi[4][Dn];
    __shared__ __align__(16) float s_o [4][Dn];   // o; later h2
    __shared__ __align__(16) float s_t1[4][Dn];   // t1; later f2h
    __shared__ __align__(16) float s_h [4][Dn];
    __shared__ __align__(16) float s_l3[4][Dn];
    __shared__ __align__(16) float s_f1[4 * DFF];

    if (t < 128) ((float4*)&s_qi[0][0])[t] = ((const float4*)(q_in + (size_t)b0*Dn))[t];
    else         ((float4*)&s_o[0][0])[t-128] = ((const float4*)(o_ws + (size_t)b0*Dn))[t-128];
    __syncthreads();

    // P6a: t1 = o @ W_out^T + b_out
    {
        int d = t & 127, gq = t >> 7;
        const float4* w4 = (const float4*)(W_out + (size_t)d * Dn);
        float a0 = 0.f, a1 = 0.f;
#pragma unroll 8
        for (int j = 0; j < 32; ++j) {
            float4 a = w4[j];
            float4 v0 = *(const float4*)&s_o[gq*2][j*4];
            float4 v1 = *(const float4*)&s_o[gq*2+1][j*4];
            a0 = fmaf(a.x,v0.x,a0); a0 = fmaf(a.y,v0.y,a0);
            a0 = fmaf(a.z,v0.z,a0); a0 = fmaf(a.w,v0.w,a0);
            a1 = fmaf(a.x,v1.x,a1); a1 = fmaf(a.y,v1.y,a1);
            a1 = fmaf(a.z,v1.z,a1); a1 = fmaf(a.w,v1.w,a1);
        }
        s_t1[gq*2][d]   = a0 + b_out[d];
        s_t1[gq*2+1][d] = a1 + b_out[d];
    }
    __syncthreads();

    // P6b: h = LN(t1, ln2) + q_in
    ln_row64<Dn>(&s_t1[wv][0], &s_h[wv][0], ln2_w, ln2_b, &s_qi[wv][0], lane);
    __syncthreads();
    // P6c: ln3h
    ln_row64<Dn>(&s_h[wv][0], &s_l3[wv][0], ln3_w, ln3_b, nullptr, lane);
    __syncthreads();

    // P6d: f1 = gelu(ln3h @ W_ff1^T + b_ff1)
    {
        int e0 = t, e1 = t + 256;
        const float4* wa = (const float4*)(W_ff1 + (size_t)e0 * Dn);
        const float4* wb = (const float4*)(W_ff1 + (size_t)e1 * Dn);
        float acc0[4] = {0,0,0,0}, acc1[4] = {0,0,0,0};
#pragma unroll 4
        for (int j = 0; j < 32; ++j) {
            float4 a = wa[j], bb = wb[j];
#pragma unroll
            for (int g = 0; g < 4; ++g) {
                float4 v = *(const float4*)&s_l3[g][j*4];
                acc0[g] = fmaf(a.x,v.x,acc0[g]);  acc0[g] = fmaf(a.y,v.y,acc0[g]);
                acc0[g] = fmaf(a.z,v.z,acc0[g]);  acc0[g] = fmaf(a.w,v.w,acc0[g]);
                acc1[g] = fmaf(bb.x,v.x,acc1[g]); acc1[g] = fmaf(bb.y,v.y,acc1[g]);
                acc1[g] = fmaf(bb.z,v.z,acc1[g]); acc1[g] = fmaf(bb.w,v.w,acc1[g]);
            }
        }
#pragma unroll
        for (int g = 0; g < 4; ++g) {
            float v0 = acc0[g] + b_ff1[e0];
            float v1 = acc1[g] + b_ff1[e1];
            s_f1[g*DFF + e0] = 0.5f * v0 * (1.f + erff(v0 * INV_SQRT2));
            s_f1[g*DFF + e1] = 0.5f * v1 * (1.f + erff(v1 * INV_SQRT2));
        }
    }
    __syncthreads();

    // P6e: LN(f1, ln4) in place
    ln_row64<DFF>(&s_f1[wv*DFF], &s_f1[wv*DFF], ln4_w, ln4_b, nullptr, lane);
    __syncthreads();

    // P6f: f2h = f1 @ W_ff2^T + b_ff2 + h -> s_t1 (dead)
    {
        int d = t & 127, gq = t >> 7;
        const float4* w4 = (const float4*)(W_ff2 + (size_t)d * DFF);
        float a0 = 0.f, a1 = 0.f;
#pragma unroll 4
        for (int j = 0; j < DFF/4; ++j) {
            float4 a = w4[j];
            float4 v0 = ((const float4*)&s_f1[(gq*2)*DFF])[j];
            float4 v1 = ((const float4*)&s_f1[(gq*2+1)*DFF])[j];
            a0 = fmaf(a.x,v0.x,a0); a0 = fmaf(a.y,v0.y,a0);
            a0 = fmaf(a.z,v0.z,a0); a0 = fmaf(a.w,v0.w,a0);
            a1 = fmaf(a.x,v1.x,a1); a1 = fmaf(a.y,v1.y,a1);
            a1 = fmaf(a.z,v1.z,a1); a1 = fmaf(a.w,v1.w,a1);
        }
        s_t1[gq*2][d]   = a0 + b_ff2[d] + s_h[gq*2][d];
        s_t1[gq*2+1][d] = a1 + b_ff2[d] + s_h[gq*2+1][d];
    }
    __syncthreads();

    // P6g: h2 = LN(ln5) -> s_o (dead)
    ln_row64<Dn>(&s_t1[wv][0], &s_o[wv][0], ln5_w, ln5_b, nullptr, lane);
    __syncthreads();

    // P6h: out = h2 @ W_head^T + b_head
    {
        int e0 = t, e1 = t + 256;
        const float4* wa = (const float4*)(W_head + (size_t)e0 * Dn);
        const float4* wb = (const float4*)(W_head + (size_t)e1 * Dn);
        float acc0[4] = {0,0,0,0}, acc1[4] = {0,0,0,0};
#pragma unroll 4
        for (int j = 0; j < 32; ++j) {
            float4 a = wa[j], bb = wb[j];
#pragma unroll
            for (int g = 0; g < 4; ++g) {
                float4 v = *(const float4*)&s_o[g][j*4];
                acc0[g] = fmaf(a.x,v.x,acc0[g]);  acc0[g] = fmaf(a.y,v.y,acc0[g]);
                acc0[g] = fmaf(a.z,v.z,acc0[g]);  acc0[g] = fmaf(a.w,v.w,acc0[g]);
                acc1[g] = fmaf(bb.x,v.x,acc1[g]); acc1[g] = fmaf(bb.y,v.y,acc1[g]);
                acc1[g] = fmaf(bb.z,v.z,acc1[g]); acc1[g] = fmaf(bb.w,v.w,acc1[g]);
            }
        }
#pragma unroll
        for (int g = 0; g < 4; ++g) {
            out[(size_t)(b0+g)*DIN + e0] = acc0[g] + b_head[e0];
            out[(size_t)(b0+g)*DIN + e1] = acc1[g] + b_head[e1];
        }
    }
}

} // namespace

extern "C" void kernel_launch(void* const* d_in, const int* in_sizes, int n_in,
                              void* d_out, int out_size, void* d_ws, size_t ws_size,
                              hipStream_t stream)
{
    const float* x      = (const float*)d_in[0];
    const float* W_in   = (const float*)d_in[1];
    const float* b_in   = (const float*)d_in[2];
    const float* pos    = (const float*)d_in[3];
    const float* mask   = (const float*)d_in[4];
    const float* mem    = (const float*)d_in[5];
    const float* ln1_w  = (const float*)d_in[6];
    const float* ln1_b  = (const float*)d_in[7];
    const float* W_qkv  = (const float*)d_in[8];
    const float* b_qkv  = (const float*)d_in[9];
    const float* W_out  = (const float*)d_in[10];
    const float* b_out  = (const float*)d_in[11];
    const float* ln2_w  = (const float*)d_in[12];
    const float* ln2_b  = (const float*)d_in[13];
    const float* ln3_w  = (const float*)d_in[14];
    const float* ln3_b  = (const float*)d_in[15];
    const float* W_ff1  = (const float*)d_in[16];
    const float* b_ff1  = (const float*)d_in[17];
    const float* ln4_w  = (const float*)d_in[18];
    const float* ln4_b  = (const float*)d_in[19];
    const float* W_ff2  = (const float*)d_in[20];
    const float* b_ff2  = (const float*)d_in[21];
    const float* ln5_w  = (const float*)d_in[22];
    const float* ln5_b  = (const float*)d_in[23];
    const float* W_head = (const float*)d_in[24];
    const float* b_head = (const float*)d_in[25];

    const int B = in_sizes[0] / DIN;   // 4096
    float* ws_qin = (float*)d_ws;                       // B*128 floats (2 MB)
    float* ws_o   = (float*)d_ws + (size_t)B * Dn;      // B*128 floats (2 MB)

    k_qin<<<dim3(B / 8), dim3(256), 0, stream>>>(x, W_in, b_in, pos, ws_qin);
    k_attn<<<dim3(B), dim3(256), 0, stream>>>(ws_qin, mask, mem,
                                              ln1_w, ln1_b, W_qkv, b_qkv, ws_o);
    k_tail<<<dim3(B / 4), dim3(256), 0, stream>>>(ws_qin, ws_o,
        W_out, b_out, ln2_w, ln2_b, ln3_w, ln3_b,
        W_ff1, b_ff1, ln4_w, ln4_b, W_ff2, b_ff2,
        ln5_w, ln5_b, W_head, b_head, (float*)d_out);
}

// Round 11
// 319.060 us; speedup vs baseline: 1.7123x; 1.0305x over previous
//
#include <hip/hip_runtime.h>

namespace {

constexpr int Dn   = 128;
constexpr int DIN  = 512;
constexpr int Hn   = 8;
constexpr int Mn   = 128;
constexpr int DFF  = 512;
constexpr float ATT_SCALE = 0.25f;
constexpr float INV_SQRT2 = 0.70710678118654752440f;

typedef short  short8v  __attribute__((ext_vector_type(8)));
typedef float  float4v  __attribute__((ext_vector_type(4)));

__device__ __forceinline__ unsigned pk_bf16(float lo, float hi) {
    unsigned r;
    asm volatile("v_cvt_pk_bf16_f32 %0, %1, %2" : "=v"(r) : "v"(lo), "v"(hi));
    return r;
}
__device__ __forceinline__ float lo16(unsigned u) { return __uint_as_float(u << 16); }
__device__ __forceinline__ float hi16(unsigned u) { return __uint_as_float(u & 0xffff0000u); }

__device__ __forceinline__ float dot128(const float* __restrict__ wrow,
                                        const float* __restrict__ v)
{
    const float4* w4 = (const float4*)wrow;
    const float4* v4 = (const float4*)v;
    float acc = 0.f;
#pragma unroll
    for (int j = 0; j < 32; ++j) {
        float4 a = w4[j], b = v4[j];
        acc += a.x*b.x + a.y*b.y + a.z*b.z + a.w*b.w;
    }
    return acc;
}

template <int NCOL>
__device__ __forceinline__ void ln_row64(const float* __restrict__ src,
                                         float* __restrict__ dst,
                                         const float* __restrict__ gw,
                                         const float* __restrict__ gb,
                                         const float* __restrict__ resid,
                                         int sub)
{
    constexpr int E = NCOL / 64;
    float v0[E]; float sm = 0.f;
#pragma unroll
    for (int i = 0; i < E; ++i) { v0[i] = src[sub*E + i]; sm += v0[i]; }
#pragma unroll
    for (int m = 32; m >= 1; m >>= 1) sm += __shfl_xor(sm, m);
    float mean = sm * (1.f / (float)NCOL);
    float vs = 0.f;
#pragma unroll
    for (int i = 0; i < E; ++i) { float d0 = v0[i] - mean; vs += d0*d0; }
#pragma unroll
    for (int m = 32; m >= 1; m >>= 1) vs += __shfl_xor(vs, m);
    float rstd = rsqrtf(vs * (1.f / (float)NCOL) + 1e-5f);
#pragma unroll
    for (int i = 0; i < E; ++i) {
        int d = sub*E + i;
        float r = (v0[i] - mean) * rstd * gw[d] + gb[d];
        dst[d] = resid ? (r + resid[d]) : r;
    }
}

//======================= Kernel A: q_in projection =======================
__global__ __launch_bounds__(256, 2)
void k_qin(const float* __restrict__ x, const float* __restrict__ W_in,
           const float* __restrict__ b_in, const float* __restrict__ pos,
           float* __restrict__ q_in)
{
    const int t  = threadIdx.x;
    const int b0 = blockIdx.x * 8;
    __shared__ __align__(16) float s_x[8 * DIN];
    {
        const float4* src = (const float4*)(x + (size_t)b0 * DIN);
        float4* dst = (float4*)s_x;
#pragma unroll
        for (int i = 0; i < 4; ++i) dst[t + 256*i] = src[t + 256*i];
    }
    __syncthreads();
    {
        int d = t & 127, gq = t >> 7;
        const float4* w4 = (const float4*)(W_in + (size_t)d * DIN);
        float acc[4] = {0,0,0,0};
        for (int j = 0; j < DIN/4; ++j) {
            float4 a = w4[j];
#pragma unroll
            for (int g = 0; g < 4; ++g) {
                float4 xv = ((const float4*)s_x)[(gq*4 + g)*(DIN/4) + j];
                acc[g] = fmaf(a.x, xv.x, acc[g]); acc[g] = fmaf(a.y, xv.y, acc[g]);
                acc[g] = fmaf(a.z, xv.z, acc[g]); acc[g] = fmaf(a.w, xv.w, acc[g]);
            }
        }
#pragma unroll
        for (int g = 0; g < 4; ++g) {
            int gb = b0 + gq*4 + g;
            q_in[(size_t)gb*Dn + d] = acc[g] + b_in[d] + pos[(size_t)gb*Dn + d];
        }
    }
}

//======================= Kernel B: attention (1 batch/block, MFMA dots) ===
__global__ __launch_bounds__(256, 2)
void k_attn(const float* __restrict__ q_in,
            const float* __restrict__ mask,
            const float* __restrict__ mem,
            const float* __restrict__ ln1_w, const float* __restrict__ ln1_b,
            const float* __restrict__ W_qkv, const float* __restrict__ b_qkv,
            float* __restrict__ o_ws)
{
    const int t    = threadIdx.x;
    const int lane = t & 63;
    const int wv   = t >> 6;
    const int b    = blockIdx.x;

    __shared__ __align__(16) unsigned short s16[Mn * Dn];   // bf16 tile, swizzled (32KB)
    // region X (5.2KB, time-multiplexed):
    //   A' bf16 [16][136] (Aq->MFMA)  ->  dots[128][10] (+rstd@8) -> qw in place
    //   ->  ctxn[8][128] (D->O)
    __shared__ __align__(16) float s_X[1312];
    __shared__ __align__(16) float s_lnq[Dn];
    __shared__ __align__(16) float s_qi[Dn];
    __shared__ __align__(16) float s_q[Dn];
    __shared__ float s_s2c[Hn], s_s0[Hn], s_den[Hn], s_p0[Hn];

    unsigned short* s_At = (unsigned short*)s_X;   // [16][136] bf16
    float* s_sc = s_X;                             // [128][10] dots/qw
    // ctxn aliases s_X as [8][128]

    if (t < 32) ((float4*)s_qi)[t] = ((const float4*)(q_in + (size_t)b*Dn))[t];
    __syncthreads();

    // S: stage tile bf16 chunk-swizzled; wave0 lnq; waves 2-3 q
    {
        const float4* src = (const float4*)(mem + (size_t)b * Mn * Dn);
#pragma unroll
        for (int i = 0; i < 16; ++i) {
            int fid = t + 256*i;
            float4 v = src[fid];
            int r = fid >> 5, k = fid & 31;
            int c = k >> 1, half = k & 1;
            unsigned u0 = pk_bf16(v.x, v.y), u1 = pk_bf16(v.z, v.w);
            *(uint2*)&s16[r*128 + ((c ^ (r & 7)) << 3) + half*4] = make_uint2(u0, u1);
        }
    }
    if (t < 64) {
        ln_row64<Dn>(s_qi, s_lnq, ln1_w, ln1_b, nullptr, t);
    } else if (t >= 128) {
        int dd = t - 128;
        s_q[dd] = dot128(W_qkv + (size_t)dd*Dn, s_qi) + b_qkv[dd];
    }
    __syncthreads();

    // Aq: A' bf16 [16][136] (s1-folded) + zero pad rows + scalars s2c/s0
    {
        int h = t >> 5, js = t & 31;
        float aq[4] = {0,0,0,0};
        float ch = 0.f;
#pragma unroll
        for (int d0 = 0; d0 < 16; ++d0) {
            float qv = s_q[h*16 + d0];
            float4 w = ((const float4*)(W_qkv + (size_t)(Dn + h*16 + d0)*Dn))[js];
            aq[0] = fmaf(qv, w.x, aq[0]); aq[1] = fmaf(qv, w.y, aq[1]);
            aq[2] = fmaf(qv, w.z, aq[2]); aq[3] = fmaf(qv, w.w, aq[3]);
            ch = fmaf(qv, b_qkv[Dn + h*16 + d0], ch);
        }
        ch *= ATT_SCALE;
        float s1p = 0.f, s2p = 0.f, s0p = 0.f;
        float aqw[4];
#pragma unroll
        for (int c = 0; c < 4; ++c) {
            int j = js*4 + c;
            float a = ATT_SCALE * aq[c];
            aqw[c] = a * ln1_w[j];
            s1p += aqw[c];
            s2p = fmaf(a, ln1_b[j], s2p);
            s0p = fmaf(a, s_lnq[j], s0p);
        }
#pragma unroll
        for (int m = 16; m >= 1; m >>= 1) {
            s1p += __shfl_xor(s1p, m, 32);
            s2p += __shfl_xor(s2p, m, 32);
            s0p += __shfl_xor(s0p, m, 32);
        }
        float sub = s1p * (1.f/128.f);
        *(unsigned*)&s_At[h*136 + 4*js]     = pk_bf16(aqw[0]-sub, aqw[1]-sub);
        *(unsigned*)&s_At[h*136 + 4*js + 2] = pk_bf16(aqw[2]-sub, aqw[3]-sub);
        if (js == 0) { s_s2c[h] = s2p + ch; s_s0[h] = s0p + ch; }
        // zero A' rows 8-15 (68 dwords per row * 8 rows = 544 dwords)
        unsigned* X32 = (unsigned*)s_At;
        for (int idx = t; idx < 544; idx += 256) X32[8*68 + idx] = 0;
    }
    __syncthreads();

    // Pass A: MFMA dots  D[16h][128r] = A'[16][128] x tile^T  + VALU row stats
    float4v acc0 = {0.f,0.f,0.f,0.f}, acc1 = {0.f,0.f,0.f,0.f};
    float rstd_reg = 0.f;
    {
        const int al = lane & 15, ag = lane >> 4;
        const int r0 = (2*wv)*16 + al, r1 = (2*wv+1)*16 + al;
#pragma unroll
        for (int ks = 0; ks < 4; ++ks) {
            short8v af = *(const short8v*)&s_At[al*136 + ks*32 + ag*8];
            int c = ks*4 + ag;
            short8v b0 = *(const short8v*)&s16[r0*128 + ((c ^ (r0 & 7)) << 3)];
            short8v b1 = *(const short8v*)&s16[r1*128 + ((c ^ (r1 & 7)) << 3)];
            acc0 = __builtin_amdgcn_mfma_f32_16x16x32_bf16(af, b0, acc0, 0, 0, 0);
            acc1 = __builtin_amdgcn_mfma_f32_16x16x32_bf16(af, b1, acc1, 0, 0, 0);
        }
        // stats: 2 threads/row
        int r = t >> 1, hf = t & 1;
        float sum = 0.f, ssq = 0.f;
#pragma unroll
        for (int kk = 0; kk < 8; ++kk) {
            int c = hf*8 + kk;
            uint4 tv = *(const uint4*)&s16[r*128 + ((c ^ (r & 7)) << 3)];
            float vv[8];
            vv[0] = lo16(tv.x); vv[1] = hi16(tv.x);
            vv[2] = lo16(tv.y); vv[3] = hi16(tv.y);
            vv[4] = lo16(tv.z); vv[5] = hi16(tv.z);
            vv[6] = lo16(tv.w); vv[7] = hi16(tv.w);
#pragma unroll
            for (int q = 0; q < 8; ++q) { sum += vv[q]; ssq = fmaf(vv[q], vv[q], ssq); }
        }
        sum += __shfl_xor(sum, 1);
        ssq += __shfl_xor(ssq, 1);
        float mean = sum * (1.f/128.f);
        float var  = fmaf(-mean, mean, ssq * (1.f/128.f));
        rstd_reg = rsqrtf(var + 1e-5f);
    }
    __syncthreads();   // all A' reads done; region X switches to dots

    // W: write dots (lanes 0-31: heads 0-7) + rstd
    {
        if (lane < 32) {
            int al = lane & 15, hb = (lane >> 4) * 4;
            int r0 = (2*wv)*16 + al, r1 = (2*wv+1)*16 + al;
#pragma unroll
            for (int reg = 0; reg < 4; ++reg) {
                s_sc[r0*10 + hb + reg] = acc0[reg];
                s_sc[r1*10 + hb + reg] = acc1[reg];
            }
        }
        if ((t & 1) == 0) s_sc[(t >> 1)*10 + 8] = rstd_reg;
    }
    __syncthreads();

    // SM: one-shot softmax; wave w -> heads 2w,2w+1; lane l -> rows 2l,2l+1
    {
        int w = wv, l = lane;
        int h0 = 2*w, h1 = h0 + 1;
        int r0 = 2*l, r1 = r0 + 1;
        float2 da = *(const float2*)&s_sc[r0*10 + h0];
        float2 db = *(const float2*)&s_sc[r1*10 + h0];
        float rs0 = s_sc[r0*10 + 8], rs1 = s_sc[r1*10 + 8];
        float2 mk = *(const float2*)&mask[(size_t)b*Mn + r0];
        float sc00 = fmaf(rs0, da.x, s_s2c[h0]) + mk.x;
        float sc01 = fmaf(rs0, da.y, s_s2c[h1]) + mk.x;
        float sc10 = fmaf(rs1, db.x, s_s2c[h0]) + mk.y;
        float sc11 = fmaf(rs1, db.y, s_s2c[h1]) + mk.y;
        float mx0 = fmaxf(sc00, sc10), mx1 = fmaxf(sc01, sc11);
#pragma unroll
        for (int m = 1; m < 64; m <<= 1) {
            mx0 = fmaxf(mx0, __shfl_xor(mx0, m));
            mx1 = fmaxf(mx1, __shfl_xor(mx1, m));
        }
        mx0 = fmaxf(mx0, s_s0[h0]);
        mx1 = fmaxf(mx1, s_s0[h1]);
        float e00 = __expf(sc00 - mx0), e10 = __expf(sc10 - mx0);
        float e01 = __expf(sc01 - mx1), e11 = __expf(sc11 - mx1);
        float ds0 = e00 + e10, ds1 = e01 + e11;
#pragma unroll
        for (int m = 1; m < 64; m <<= 1) {
            ds0 += __shfl_xor(ds0, m);
            ds1 += __shfl_xor(ds1, m);
        }
        float p00 = __expf(s_s0[h0] - mx0), p01 = __expf(s_s0[h1] - mx1);
        *(float2*)&s_sc[r0*10 + h0] = make_float2(e00*rs0, e01*rs0);
        *(float2*)&s_sc[r1*10 + h0] = make_float2(e10*rs1, e11*rs1);
        if (l == 0) {
            s_den[h0] = ds0 + p00; s_p0[h0] = p00;
            s_den[h1] = ds1 + p01; s_p0[h1] = p01;
        }
    }
    __syncthreads();

    // C: ctx (wave = head pair; quarter = 32 rows; lane chunk = 8 cols)
    float cx0[8], cx1[8], cS0, cS1;
    {
        int w = wv, l = lane;
        int qtr = l >> 4, c = l & 15;
#pragma unroll
        for (int q = 0; q < 8; ++q) { cx0[q] = 0.f; cx1[q] = 0.f; }
#pragma unroll 4
        for (int rr = 0; rr < 32; ++rr) {
            int r = qtr*32 + rr;
            uint4 tv = *(const uint4*)&s16[r*128 + ((c ^ (r & 7)) << 3)];
            float2 qv = *(const float2*)&s_sc[r*10 + 2*w];
            float v0 = lo16(tv.x), v1 = hi16(tv.x);
            float v2 = lo16(tv.y), v3 = hi16(tv.y);
            float v4 = lo16(tv.z), v5 = hi16(tv.z);
            float v6 = lo16(tv.w), v7 = hi16(tv.w);
            cx0[0]=fmaf(qv.x,v0,cx0[0]); cx1[0]=fmaf(qv.y,v0,cx1[0]);
            cx0[1]=fmaf(qv.x,v1,cx0[1]); cx1[1]=fmaf(qv.y,v1,cx1[1]);
            cx0[2]=fmaf(qv.x,v2,cx0[2]); cx1[2]=fmaf(qv.y,v2,cx1[2]);
            cx0[3]=fmaf(qv.x,v3,cx0[3]); cx1[3]=fmaf(qv.y,v3,cx1[3]);
            cx0[4]=fmaf(qv.x,v4,cx0[4]); cx1[4]=fmaf(qv.y,v4,cx1[4]);
            cx0[5]=fmaf(qv.x,v5,cx0[5]); cx1[5]=fmaf(qv.y,v5,cx1[5]);
            cx0[6]=fmaf(qv.x,v6,cx0[6]); cx1[6]=fmaf(qv.y,v6,cx1[6]);
            cx0[7]=fmaf(qv.x,v7,cx0[7]); cx1[7]=fmaf(qv.y,v7,cx1[7]);
        }
#pragma unroll
        for (int q = 0; q < 8; ++q) {
            cx0[q] += __shfl_xor(cx0[q], 16);
            cx0[q] += __shfl_xor(cx0[q], 32);
            cx1[q] += __shfl_xor(cx1[q], 16);
            cx1[q] += __shfl_xor(cx1[q], 32);
        }
        float sA = ((cx0[0]+cx0[1])+(cx0[2]+cx0[3])) + ((cx0[4]+cx0[5])+(cx0[6]+cx0[7]));
        float sB = ((cx1[0]+cx1[1])+(cx1[2]+cx1[3])) + ((cx1[4]+cx1[5])+(cx1[6]+cx1[7]));
#pragma unroll
        for (int m = 1; m < 16; m <<= 1) {
            sA += __shfl_xor(sA, m);
            sB += __shfl_xor(sB, m);
        }
        cS0 = sA * (1.f/128.f);
        cS1 = sB * (1.f/128.f);
    }
    __syncthreads();   // qw reads done before ctxn overwrites region X

    // D: verified fold -> ctxn[8][128] into region X
    if (lane < 16) {
        int c = lane;
        int h0 = 2*wv, h1 = h0 + 1;
        float den0 = s_den[h0], p0a = s_p0[h0], sP0 = den0 - p0a, inv0 = 1.f/den0;
        float den1 = s_den[h1], p0b = s_p0[h1], sP1 = den1 - p0b, inv1 = 1.f/den1;
#pragma unroll
        for (int q = 0; q < 2; ++q) {
            int j0 = c*8 + q*4;
            float4 lq = *(const float4*)&s_lnq[j0];
            float4 lw = *(const float4*)&ln1_w[j0];
            float4 lb = *(const float4*)&ln1_b[j0];
            float4 o0, o1;
            o0.x = (p0a*lq.x + lw.x*(cx0[q*4+0]-cS0) + lb.x*sP0) * inv0;
            o0.y = (p0a*lq.y + lw.y*(cx0[q*4+1]-cS0) + lb.y*sP0) * inv0;
            o0.z = (p0a*lq.z + lw.z*(cx0[q*4+2]-cS0) + lb.z*sP0) * inv0;
            o0.w = (p0a*lq.w + lw.w*(cx0[q*4+3]-cS0) + lb.w*sP0) * inv0;
            o1.x = (p0b*lq.x + lw.x*(cx1[q*4+0]-cS1) + lb.x*sP1) * inv1;
            o1.y = (p0b*lq.y + lw.y*(cx1[q*4+1]-cS1) + lb.y*sP1) * inv1;
            o1.z = (p0b*lq.z + lw.z*(cx1[q*4+2]-cS1) + lb.z*sP1) * inv1;
            o1.w = (p0b*lq.w + lw.w*(cx1[q*4+3]-cS1) + lb.w*sP1) * inv1;
            *(float4*)&s_X[h0*128 + j0] = o0;
            *(float4*)&s_X[h1*128 + j0] = o1;
        }
    }
    __syncthreads();

    // O: o = Wv @ ctxn + bv  (2 threads/output, K-split 64/64)
    {
        int d = t >> 1, half = t & 1;
        int h = d >> 4;
        const float4* w4 = (const float4*)(W_qkv + (size_t)(2*Dn + d)*Dn) + half*16;
        const float4* c4 = (const float4*)&s_X[h*128] + half*16;
        float acc = 0.f;
#pragma unroll
        for (int j = 0; j < 16; ++j) {
            float4 a = w4[j], v = c4[j];
            acc += a.x*v.x + a.y*v.y + a.z*v.z + a.w*v.w;
        }
        acc += __shfl_xor(acc, 1);
        if (half == 0)
            o_ws[(size_t)b*Dn + d] = acc + b_qkv[2*Dn + d];
    }
}

//======================= Kernel C: MLP tail (4 batches/block) =============
__global__ __launch_bounds__(256, 2)
void k_tail(const float* __restrict__ q_in, const float* __restrict__ o_ws,
            const float* __restrict__ W_out, const float* __restrict__ b_out,
            const float* __restrict__ ln2_w, const float* __restrict__ ln2_b,
            const float* __restrict__ ln3_w, const float* __restrict__ ln3_b,
            const float* __restrict__ W_ff1, const float* __restrict__ b_ff1,
            const float* __restrict__ ln4_w, const float* __restrict__ ln4_b,
            const float* __restrict__ W_ff2, const float* __restrict__ b_ff2,
            const float* __restrict__ ln5_w, const float* __restrict__ ln5_b,
            const float* __restrict__ W_head, const float* __restrict__ b_head,
            float* __restrict__ out)
{
    const int t    = threadIdx.x;
    const int lane = t & 63;
    const int wv   = t >> 6;
    const int b0   = blockIdx.x * 4;

    __shared__ __align__(16) float s_qi[4][Dn];
    __shared__ __align__(16) float s_o [4][Dn];
    __shared__ __align__(16) float s_t1[4][Dn];
    __shared__ __align__(16) float s_h [4][Dn];
    __shared__ __align__(16) float s_l3[4][Dn];
    __shared__ __align__(16) float s_f1[4 * DFF];

    if (t < 128) ((float4*)&s_qi[0][0])[t] = ((const float4*)(q_in + (size_t)b0*Dn))[t];
    else         ((float4*)&s_o[0][0])[t-128] = ((const float4*)(o_ws + (size_t)b0*Dn))[t-128];
    __syncthreads();

    {
        int d = t & 127, gq = t >> 7;
        const float4* w4 = (const float4*)(W_out + (size_t)d * Dn);
        float a0 = 0.f, a1 = 0.f;
#pragma unroll 8
        for (int j = 0; j < 32; ++j) {
            float4 a = w4[j];
            float4 v0 = *(const float4*)&s_o[gq*2][j*4];
            float4 v1 = *(const float4*)&s_o[gq*2+1][j*4];
            a0 = fmaf(a.x,v0.x,a0); a0 = fmaf(a.y,v0.y,a0);
            a0 = fmaf(a.z,v0.z,a0); a0 = fmaf(a.w,v0.w,a0);
            a1 = fmaf(a.x,v1.x,a1); a1 = fmaf(a.y,v1.y,a1);
            a1 = fmaf(a.z,v1.z,a1); a1 = fmaf(a.w,v1.w,a1);
        }
        s_t1[gq*2][d]   = a0 + b_out[d];
        s_t1[gq*2+1][d] = a1 + b_out[d];
    }
    __syncthreads();

    ln_row64<Dn>(&s_t1[wv][0], &s_h[wv][0], ln2_w, ln2_b, &s_qi[wv][0], lane);
    __syncthreads();
    ln_row64<Dn>(&s_h[wv][0], &s_l3[wv][0], ln3_w, ln3_b, nullptr, lane);
    __syncthreads();

    {
        int e0 = t, e1 = t + 256;
        const float4* wa = (const float4*)(W_ff1 + (size_t)e0 * Dn);
        const float4* wb = (const float4*)(W_ff1 + (size_t)e1 * Dn);
        float acc0[4] = {0,0,0,0}, acc1[4] = {0,0,0,0};
#pragma unroll 4
        for (int j = 0; j < 32; ++j) {
            float4 a = wa[j], bb = wb[j];
#pragma unroll
            for (int g = 0; g < 4; ++g) {
                float4 v = *(const float4*)&s_l3[g][j*4];
                acc0[g] = fmaf(a.x,v.x,acc0[g]);  acc0[g] = fmaf(a.y,v.y,acc0[g]);
                acc0[g] = fmaf(a.z,v.z,acc0[g]);  acc0[g] = fmaf(a.w,v.w,acc0[g]);
                acc1[g] = fmaf(bb.x,v.x,acc1[g]); acc1[g] = fmaf(bb.y,v.y,acc1[g]);
                acc1[g] = fmaf(bb.z,v.z,acc1[g]); acc1[g] = fmaf(bb.w,v.w,acc1[g]);
            }
        }
#pragma unroll
        for (int g = 0; g < 4; ++g) {
            float v0 = acc0[g] + b_ff1[e0];
            float v1 = acc1[g] + b_ff1[e1];
            s_f1[g*DFF + e0] = 0.5f * v0 * (1.f + erff(v0 * INV_SQRT2));
            s_f1[g*DFF + e1] = 0.5f * v1 * (1.f + erff(v1 * INV_SQRT2));
        }
    }
    __syncthreads();

    ln_row64<DFF>(&s_f1[wv*DFF], &s_f1[wv*DFF], ln4_w, ln4_b, nullptr, lane);
    __syncthreads();

    {
        int d = t & 127, gq = t >> 7;
        const float4* w4 = (const float4*)(W_ff2 + (size_t)d * DFF);
        float a0 = 0.f, a1 = 0.f;
#pragma unroll 4
        for (int j = 0; j < DFF/4; ++j) {
            float4 a = w4[j];
            float4 v0 = ((const float4*)&s_f1[(gq*2)*DFF])[j];
            float4 v1 = ((const float4*)&s_f1[(gq*2+1)*DFF])[j];
            a0 = fmaf(a.x,v0.x,a0); a0 = fmaf(a.y,v0.y,a0);
            a0 = fmaf(a.z,v0.z,a0); a0 = fmaf(a.w,v0.w,a0);
            a1 = fmaf(a.x,v1.x,a1); a1 = fmaf(a.y,v1.y,a1);
            a1 = fmaf(a.z,v1.z,a1); a1 = fmaf(a.w,v1.w,a1);
        }
        s_t1[gq*2][d]   = a0 + b_ff2[d] + s_h[gq*2][d];
        s_t1[gq*2+1][d] = a1 + b_ff2[d] + s_h[gq*2+1][d];
    }
    __syncthreads();

    ln_row64<Dn>(&s_t1[wv][0], &s_o[wv][0], ln5_w, ln5_b, nullptr, lane);
    __syncthreads();

    {
        int e0 = t, e1 = t + 256;
        const float4* wa = (const float4*)(W_head + (size_t)e0 * Dn);
        const float4* wb = (const float4*)(W_head + (size_t)e1 * Dn);
        float acc0[4] = {0,0,0,0}, acc1[4] = {0,0,0,0};
#pragma unroll 4
        for (int j = 0; j < 32; ++j) {
            float4 a = wa[j], bb = wb[j];
#pragma unroll
            for (int g = 0; g < 4; ++g) {
                float4 v = *(const float4*)&s_o[g][j*4];
                acc0[g] = fmaf(a.x,v.x,acc0[g]);  acc0[g] = fmaf(a.y,v.y,acc0[g]);
                acc0[g] = fmaf(a.z,v.z,acc0[g]);  acc0[g] = fmaf(a.w,v.w,acc0[g]);
                acc1[g] = fmaf(bb.x,v.x,acc1[g]); acc1[g] = fmaf(bb.y,v.y,acc1[g]);
                acc1[g] = fmaf(bb.z,v.z,acc1[g]); acc1[g] = fmaf(bb.w,v.w,acc1[g]);
            }
        }
#pragma unroll
        for (int g = 0; g < 4; ++g) {
            out[(size_t)(b0+g)*DIN + e0] = acc0[g] + b_head[e0];
            out[(size_t)(b0+g)*DIN + e1] = acc1[g] + b_head[e1];
        }
    }
}

} // namespace

extern "C" void kernel_launch(void* const* d_in, const int* in_sizes, int n_in,
                              void* d_out, int out_size, void* d_ws, size_t ws_size,
                              hipStream_t stream)
{
    const float* x      = (const float*)d_in[0];
    const float* W_in   = (const float*)d_in[1];
    const float* b_in   = (const float*)d_in[2];
    const float* pos    = (const float*)d_in[3];
    const float* mask   = (const float*)d_in[4];
    const float* mem    = (const float*)d_in[5];
    const float* ln1_w  = (const float*)d_in[6];
    const float* ln1_b  = (const float*)d_in[7];
    const float* W_qkv  = (const float*)d_in[8];
    const float* b_qkv  = (const float*)d_in[9];
    const float* W_out  = (const float*)d_in[10];
    const float* b_out  = (const float*)d_in[11];
    const float* ln2_w  = (const float*)d_in[12];
    const float* ln2_b  = (const float*)d_in[13];
    const float* ln3_w  = (const float*)d_in[14];
    const float* ln3_b  = (const float*)d_in[15];
    const float* W_ff1  = (const float*)d_in[16];
    const float* b_ff1  = (const float*)d_in[17];
    const float* ln4_w  = (const float*)d_in[18];
    const float* ln4_b  = (const float*)d_in[19];
    const float* W_ff2  = (const float*)d_in[20];
    const float* b_ff2  = (const float*)d_in[21];
    const float* ln5_w  = (const float*)d_in[22];
    const float* ln5_b  = (const float*)d_in[23];
    const float* W_head = (const float*)d_in[24];
    const float* b_head = (const float*)d_in[25];

    const int B = in_sizes[0] / DIN;   // 4096
    float* ws_qin = (float*)d_ws;                       // B*128 floats (2 MB)
    float* ws_o   = (float*)d_ws + (size_t)B * Dn;      // B*128 floats (2 MB)

    k_qin<<<dim3(B / 8), dim3(256), 0, stream>>>(x, W_in, b_in, pos, ws_qin);
    k_attn<<<dim3(B), dim3(256), 0, stream>>>(ws_qin, mask, mem,
                                              ln1_w, ln1_b, W_qkv, b_qkv, ws_o);
    k_tail<<<dim3(B / 4), dim3(256), 0, stream>>>(ws_qin, ws_o,
        W_out, b_out, ln2_w, ln2_b, ln3_w, ln3_b,
        W_ff1, b_ff1, ln4_w, ln4_b, W_ff2, b_ff2,
        ln5_w, ln5_b, W_head, b_head, (float*)d_out);
}

// Round 13
// 268.542 us; speedup vs baseline: 2.0344x; 1.1881x over previous
//
#include <hip/hip_runtime.h>

namespace {

constexpr int Dn   = 128;
constexpr int DIN  = 512;
constexpr int Hn   = 8;
constexpr int Mn   = 128;
constexpr int DFF  = 512;
constexpr int GA   = 4;     // batches per k_attn block (pipelined)
constexpr int GC   = 8;     // batches per k_tail block
constexpr float ATT_SCALE = 0.25f;
constexpr float INV_SQRT2 = 0.70710678118654752440f;

typedef short  short8v  __attribute__((ext_vector_type(8)));
typedef float  float4v  __attribute__((ext_vector_type(4)));

__device__ __forceinline__ unsigned pk_bf16(float lo, float hi) {
    unsigned r;
    asm volatile("v_cvt_pk_bf16_f32 %0, %1, %2" : "=v"(r) : "v"(lo), "v"(hi));
    return r;
}
__device__ __forceinline__ float lo16(unsigned u) { return __uint_as_float(u << 16); }
__device__ __forceinline__ float hi16(unsigned u) { return __uint_as_float(u & 0xffff0000u); }

__device__ __forceinline__ float dot128(const float* __restrict__ wrow,
                                        const float* __restrict__ v)
{
    const float4* w4 = (const float4*)wrow;
    const float4* v4 = (const float4*)v;
    float acc = 0.f;
#pragma unroll
    for (int j = 0; j < 32; ++j) {
        float4 a = w4[j], b = v4[j];
        acc += a.x*b.x + a.y*b.y + a.z*b.z + a.w*b.w;
    }
    return acc;
}

template <int NCOL>
__device__ __forceinline__ void ln_row64(const float* __restrict__ src,
                                         float* __restrict__ dst,
                                         const float* __restrict__ gw,
                                         const float* __restrict__ gb,
                                         const float* __restrict__ resid,
                                         int sub)
{
    constexpr int E = NCOL / 64;
    float v0[E]; float sm = 0.f;
#pragma unroll
    for (int i = 0; i < E; ++i) { v0[i] = src[sub*E + i]; sm += v0[i]; }
#pragma unroll
    for (int m = 32; m >= 1; m >>= 1) sm += __shfl_xor(sm, m);
    float mean = sm * (1.f / (float)NCOL);
    float vs = 0.f;
#pragma unroll
    for (int i = 0; i < E; ++i) { float d0 = v0[i] - mean; vs += d0*d0; }
#pragma unroll
    for (int m = 32; m >= 1; m >>= 1) vs += __shfl_xor(vs, m);
    float rstd = rsqrtf(vs * (1.f / (float)NCOL) + 1e-5f);
#pragma unroll
    for (int i = 0; i < E; ++i) {
        int d = sub*E + i;
        float r = (v0[i] - mean) * rstd * gw[d] + gb[d];
        dst[d] = resid ? (r + resid[d]) : r;
    }
}

//======================= Kernel A: q_in projection =======================
__global__ __launch_bounds__(256, 2)
void k_qin(const float* __restrict__ x, const float* __restrict__ W_in,
           const float* __restrict__ b_in, const float* __restrict__ pos,
           float* __restrict__ q_in)
{
    const int t  = threadIdx.x;
    const int b0 = blockIdx.x * 8;
    __shared__ __align__(16) float s_x[8 * DIN];
    {
        const float4* src = (const float4*)(x + (size_t)b0 * DIN);
        float4* dst = (float4*)s_x;
#pragma unroll
        for (int i = 0; i < 4; ++i) dst[t + 256*i] = src[t + 256*i];
    }
    __syncthreads();
    {
        int d = t & 127, gq = t >> 7;
        const float4* w4 = (const float4*)(W_in + (size_t)d * DIN);
        float acc[4] = {0,0,0,0};
        for (int j = 0; j < DIN/4; ++j) {
            float4 a = w4[j];
#pragma unroll
            for (int g = 0; g < 4; ++g) {
                float4 xv = ((const float4*)s_x)[(gq*4 + g)*(DIN/4) + j];
                acc[g] = fmaf(a.x, xv.x, acc[g]); acc[g] = fmaf(a.y, xv.y, acc[g]);
                acc[g] = fmaf(a.z, xv.z, acc[g]); acc[g] = fmaf(a.w, xv.w, acc[g]);
            }
        }
#pragma unroll
        for (int g = 0; g < 4; ++g) {
            int gb = b0 + gq*4 + g;
            q_in[(size_t)gb*Dn + d] = acc[g] + b_in[d] + pos[(size_t)gb*Dn + d];
        }
    }
}

//=========== Kernel B: attention, 4 batches/block, double-buffered ========
__global__ __launch_bounds__(256, 2)
void k_attn(const float* __restrict__ q_in,
            const float* __restrict__ mask,
            const float* __restrict__ mem,
            const float* __restrict__ ln1_w, const float* __restrict__ ln1_b,
            const float* __restrict__ W_qkv, const float* __restrict__ b_qkv,
            float* __restrict__ o_ws)
{
    const int t    = threadIdx.x;
    const int lane = t & 63;
    const int wv   = t >> 6;
    const int b0   = blockIdx.x * GA;

    __shared__ __align__(16) unsigned short s16[2][Mn * Dn]; // 2x32KB bf16 tiles
    __shared__ __align__(16) float s_X[1312];   // A' -> dots/qw -> ctxn
    __shared__ __align__(16) float s_lnq[Dn];
    __shared__ __align__(16) float s_q[Dn];
    __shared__ __align__(16) float s_qin[GA][Dn];
    __shared__ float s_s2c[Hn], s_s0[Hn], s_den[Hn], s_p0[Hn];

    unsigned short* s_At = (unsigned short*)s_X;   // [16][136] bf16
    float* s_sc = s_X;                             // [128][10] dots/qw

    // prologue: issue loads for batch 0; stage all 4 q_in rows
    float4 pr[16];
    {
        const float4* src = (const float4*)(mem + (size_t)b0 * Mn * Dn);
#pragma unroll
        for (int i = 0; i < 16; ++i) pr[i] = src[t + 256*i];
    }
    if (t < 128)
        ((float4*)&s_qin[0][0])[t] = ((const float4*)(q_in + (size_t)b0*Dn))[t];
    // r12 BUG: missing barrier here let waves 2-3 read s_qin[0] (written by
    // waves 0-1) before the write landed -> absmax 1.85. One barrier fixes it.
    __syncthreads();

    for (int g = 0; g < GA; ++g) {
        const int p = g & 1;

        // W: convert+write the in-flight registers into buf p (T14 write-late)
#pragma unroll
        for (int i = 0; i < 16; ++i) {
            int fid = t + 256*i;
            int r = fid >> 5, k = fid & 31;
            int c = k >> 1, half = k & 1;
            unsigned u0 = pk_bf16(pr[i].x, pr[i].y), u1 = pk_bf16(pr[i].z, pr[i].w);
            *(uint2*)&s16[p][r*128 + ((c ^ (r & 7)) << 3) + half*4] = make_uint2(u0, u1);
        }
        // issue next batch's loads immediately (T14 issue-early)
        if (g + 1 < GA) {
            const float4* src = (const float4*)(mem + (size_t)(b0+g+1) * Mn * Dn);
#pragma unroll
            for (int i = 0; i < 16; ++i) pr[i] = src[t + 256*i];
        }
        // lnq (wave 0) and q (waves 2-3) for batch g
        if (t < 64) {
            ln_row64<Dn>(&s_qin[g][0], s_lnq, ln1_w, ln1_b, nullptr, t);
        } else if (t >= 128) {
            int dd = t - 128;
            s_q[dd] = dot128(W_qkv + (size_t)dd*Dn, &s_qin[g][0]) + b_qkv[dd];
        }
        __syncthreads();

        // Aq: A' bf16 [16][136] (s1-folded) + zero pad rows + scalars s2c/s0
        {
            int h = t >> 5, js = t & 31;
            float aq[4] = {0,0,0,0};
            float ch = 0.f;
#pragma unroll
            for (int d0 = 0; d0 < 16; ++d0) {
                float qv = s_q[h*16 + d0];
                float4 w = ((const float4*)(W_qkv + (size_t)(Dn + h*16 + d0)*Dn))[js];
                aq[0] = fmaf(qv, w.x, aq[0]); aq[1] = fmaf(qv, w.y, aq[1]);
                aq[2] = fmaf(qv, w.z, aq[2]); aq[3] = fmaf(qv, w.w, aq[3]);
                ch = fmaf(qv, b_qkv[Dn + h*16 + d0], ch);
            }
            ch *= ATT_SCALE;
            float s1p = 0.f, s2p = 0.f, s0p = 0.f;
            float aqw[4];
#pragma unroll
            for (int c = 0; c < 4; ++c) {
                int j = js*4 + c;
                float a = ATT_SCALE * aq[c];
                aqw[c] = a * ln1_w[j];
                s1p += aqw[c];
                s2p = fmaf(a, ln1_b[j], s2p);
                s0p = fmaf(a, s_lnq[j], s0p);
            }
#pragma unroll
            for (int m = 16; m >= 1; m >>= 1) {
                s1p += __shfl_xor(s1p, m, 32);
                s2p += __shfl_xor(s2p, m, 32);
                s0p += __shfl_xor(s0p, m, 32);
            }
            float sub = s1p * (1.f/128.f);
            *(unsigned*)&s_At[h*136 + 4*js]     = pk_bf16(aqw[0]-sub, aqw[1]-sub);
            *(unsigned*)&s_At[h*136 + 4*js + 2] = pk_bf16(aqw[2]-sub, aqw[3]-sub);
            if (js == 0) { s_s2c[h] = s2p + ch; s_s0[h] = s0p + ch; }
            unsigned* X32 = (unsigned*)s_At;
            for (int idx = t; idx < 544; idx += 256) X32[8*68 + idx] = 0;
        }
        __syncthreads();

        // Pass A: MFMA dots + VALU row stats (on buf p)
        float4v acc0 = {0.f,0.f,0.f,0.f}, acc1 = {0.f,0.f,0.f,0.f};
        float rstd_reg = 0.f;
        {
            const int al = lane & 15, ag = lane >> 4;
            const int r0 = (2*wv)*16 + al, r1 = (2*wv+1)*16 + al;
#pragma unroll
            for (int ks = 0; ks < 4; ++ks) {
                short8v af = *(const short8v*)&s_At[al*136 + ks*32 + ag*8];
                int c = ks*4 + ag;
                short8v f0 = *(const short8v*)&s16[p][r0*128 + ((c ^ (r0 & 7)) << 3)];
                short8v f1 = *(const short8v*)&s16[p][r1*128 + ((c ^ (r1 & 7)) << 3)];
                acc0 = __builtin_amdgcn_mfma_f32_16x16x32_bf16(af, f0, acc0, 0, 0, 0);
                acc1 = __builtin_amdgcn_mfma_f32_16x16x32_bf16(af, f1, acc1, 0, 0, 0);
            }
            int r = t >> 1, hf = t & 1;
            float sum = 0.f, ssq = 0.f;
#pragma unroll
            for (int kk = 0; kk < 8; ++kk) {
                int c = hf*8 + kk;
                uint4 tv = *(const uint4*)&s16[p][r*128 + ((c ^ (r & 7)) << 3)];
                float vv[8];
                vv[0] = lo16(tv.x); vv[1] = hi16(tv.x);
                vv[2] = lo16(tv.y); vv[3] = hi16(tv.y);
                vv[4] = lo16(tv.z); vv[5] = hi16(tv.z);
                vv[6] = lo16(tv.w); vv[7] = hi16(tv.w);
#pragma unroll
                for (int q = 0; q < 8; ++q) { sum += vv[q]; ssq = fmaf(vv[q], vv[q], ssq); }
            }
            sum += __shfl_xor(sum, 1);
            ssq += __shfl_xor(ssq, 1);
            float mean = sum * (1.f/128.f);
            float var  = fmaf(-mean, mean, ssq * (1.f/128.f));
            rstd_reg = rsqrtf(var + 1e-5f);
        }
        __syncthreads();   // A' reads done; region X switches to dots

        // Wdots: write dots + rstd
        {
            if (lane < 32) {
                int al = lane & 15, hb = (lane >> 4) * 4;
                int r0 = (2*wv)*16 + al, r1 = (2*wv+1)*16 + al;
#pragma unroll
                for (int reg = 0; reg < 4; ++reg) {
                    s_sc[r0*10 + hb + reg] = acc0[reg];
                    s_sc[r1*10 + hb + reg] = acc1[reg];
                }
            }
            if ((t & 1) == 0) s_sc[(t >> 1)*10 + 8] = rstd_reg;
        }
        __syncthreads();

        // SM: one-shot softmax; wave w -> heads 2w,2w+1; lane l -> rows 2l,2l+1
        {
            int w = wv, l = lane;
            int h0 = 2*w, h1 = h0 + 1;
            int r0 = 2*l, r1 = r0 + 1;
            float2 da = *(const float2*)&s_sc[r0*10 + h0];
            float2 db = *(const float2*)&s_sc[r1*10 + h0];
            float rs0 = s_sc[r0*10 + 8], rs1 = s_sc[r1*10 + 8];
            float2 mk = *(const float2*)&mask[(size_t)(b0+g)*Mn + r0];
            float sc00 = fmaf(rs0, da.x, s_s2c[h0]) + mk.x;
            float sc01 = fmaf(rs0, da.y, s_s2c[h1]) + mk.x;
            float sc10 = fmaf(rs1, db.x, s_s2c[h0]) + mk.y;
            float sc11 = fmaf(rs1, db.y, s_s2c[h1]) + mk.y;
            float mx0 = fmaxf(sc00, sc10), mx1 = fmaxf(sc01, sc11);
#pragma unroll
            for (int m = 1; m < 64; m <<= 1) {
                mx0 = fmaxf(mx0, __shfl_xor(mx0, m));
                mx1 = fmaxf(mx1, __shfl_xor(mx1, m));
            }
            mx0 = fmaxf(mx0, s_s0[h0]);
            mx1 = fmaxf(mx1, s_s0[h1]);
            float e00 = __expf(sc00 - mx0), e10 = __expf(sc10 - mx0);
            float e01 = __expf(sc01 - mx1), e11 = __expf(sc11 - mx1);
            float ds0 = e00 + e10, ds1 = e01 + e11;
#pragma unroll
            for (int m = 1; m < 64; m <<= 1) {
                ds0 += __shfl_xor(ds0, m);
                ds1 += __shfl_xor(ds1, m);
            }
            float p00 = __expf(s_s0[h0] - mx0), p01 = __expf(s_s0[h1] - mx1);
            *(float2*)&s_sc[r0*10 + h0] = make_float2(e00*rs0, e01*rs0);
            *(float2*)&s_sc[r1*10 + h0] = make_float2(e10*rs1, e11*rs1);
            if (l == 0) {
                s_den[h0] = ds0 + p00; s_p0[h0] = p00;
                s_den[h1] = ds1 + p01; s_p0[h1] = p01;
            }
        }
        __syncthreads();

        // C: ctx (wave = head pair; quarter = 32 rows; lane chunk = 8 cols)
        float cx0[8], cx1[8], cS0, cS1;
        {
            int w = wv, l = lane;
            int qtr = l >> 4, c = l & 15;
#pragma unroll
            for (int q = 0; q < 8; ++q) { cx0[q] = 0.f; cx1[q] = 0.f; }
#pragma unroll 4
            for (int rr = 0; rr < 32; ++rr) {
                int r = qtr*32 + rr;
                uint4 tv = *(const uint4*)&s16[p][r*128 + ((c ^ (r & 7)) << 3)];
                float2 qv = *(const float2*)&s_sc[r*10 + 2*w];
                float v0 = lo16(tv.x), v1 = hi16(tv.x);
                float v2 = lo16(tv.y), v3 = hi16(tv.y);
                float v4 = lo16(tv.z), v5 = hi16(tv.z);
                float v6 = lo16(tv.w), v7 = hi16(tv.w);
                cx0[0]=fmaf(qv.x,v0,cx0[0]); cx1[0]=fmaf(qv.y,v0,cx1[0]);
                cx0[1]=fmaf(qv.x,v1,cx0[1]); cx1[1]=fmaf(qv.y,v1,cx1[1]);
                cx0[2]=fmaf(qv.x,v2,cx0[2]); cx1[2]=fmaf(qv.y,v2,cx1[2]);
                cx0[3]=fmaf(qv.x,v3,cx0[3]); cx1[3]=fmaf(qv.y,v3,cx1[3]);
                cx0[4]=fmaf(qv.x,v4,cx0[4]); cx1[4]=fmaf(qv.y,v4,cx1[4]);
                cx0[5]=fmaf(qv.x,v5,cx0[5]); cx1[5]=fmaf(qv.y,v5,cx1[5]);
                cx0[6]=fmaf(qv.x,v6,cx0[6]); cx1[6]=fmaf(qv.y,v6,cx1[6]);
                cx0[7]=fmaf(qv.x,v7,cx0[7]); cx1[7]=fmaf(qv.y,v7,cx1[7]);
            }
#pragma unroll
            for (int q = 0; q < 8; ++q) {
                cx0[q] += __shfl_xor(cx0[q], 16);
                cx0[q] += __shfl_xor(cx0[q], 32);
                cx1[q] += __shfl_xor(cx1[q], 16);
                cx1[q] += __shfl_xor(cx1[q], 32);
            }
            float sA = ((cx0[0]+cx0[1])+(cx0[2]+cx0[3])) + ((cx0[4]+cx0[5])+(cx0[6]+cx0[7]));
            float sB = ((cx1[0]+cx1[1])+(cx1[2]+cx1[3])) + ((cx1[4]+cx1[5])+(cx1[6]+cx1[7]));
#pragma unroll
            for (int m = 1; m < 16; m <<= 1) {
                sA += __shfl_xor(sA, m);
                sB += __shfl_xor(sB, m);
            }
            cS0 = sA * (1.f/128.f);
            cS1 = sB * (1.f/128.f);
        }
        __syncthreads();   // qw reads done before ctxn overwrites region X

        // D: verified fold -> ctxn[8][128] into region X
        if (lane < 16) {
            int c = lane;
            int h0 = 2*wv, h1 = h0 + 1;
            float den0 = s_den[h0], p0a = s_p0[h0], sP0 = den0 - p0a, inv0 = 1.f/den0;
            float den1 = s_den[h1], p0b = s_p0[h1], sP1 = den1 - p0b, inv1 = 1.f/den1;
#pragma unroll
            for (int q = 0; q < 2; ++q) {
                int j0 = c*8 + q*4;
                float4 lq = *(const float4*)&s_lnq[j0];
                float4 lw = *(const float4*)&ln1_w[j0];
                float4 lb = *(const float4*)&ln1_b[j0];
                float4 o0, o1;
                o0.x = (p0a*lq.x + lw.x*(cx0[q*4+0]-cS0) + lb.x*sP0) * inv0;
                o0.y = (p0a*lq.y + lw.y*(cx0[q*4+1]-cS0) + lb.y*sP0) * inv0;
                o0.z = (p0a*lq.z + lw.z*(cx0[q*4+2]-cS0) + lb.z*sP0) * inv0;
                o0.w = (p0a*lq.w + lw.w*(cx0[q*4+3]-cS0) + lb.w*sP0) * inv0;
                o1.x = (p0b*lq.x + lw.x*(cx1[q*4+0]-cS1) + lb.x*sP1) * inv1;
                o1.y = (p0b*lq.y + lw.y*(cx1[q*4+1]-cS1) + lb.y*sP1) * inv1;
                o1.z = (p0b*lq.z + lw.z*(cx1[q*4+2]-cS1) + lb.z*sP1) * inv1;
                o1.w = (p0b*lq.w + lw.w*(cx1[q*4+3]-cS1) + lb.w*sP1) * inv1;
                *(float4*)&s_X[h0*128 + j0] = o0;
                *(float4*)&s_X[h1*128 + j0] = o1;
            }
        }
        __syncthreads();

        // O: o = Wv @ ctxn + bv  (2 threads/output, K-split 64/64)
        {
            int d = t >> 1, half = t & 1;
            int h = d >> 4;
            const float4* w4 = (const float4*)(W_qkv + (size_t)(2*Dn + d)*Dn) + half*16;
            const float4* c4 = (const float4*)&s_X[h*128] + half*16;
            float acc = 0.f;
#pragma unroll
            for (int j = 0; j < 16; ++j) {
                float4 a = w4[j], v = c4[j];
                acc += a.x*v.x + a.y*v.y + a.z*v.z + a.w*v.w;
            }
            acc += __shfl_xor(acc, 1);
            if (half == 0)
                o_ws[(size_t)(b0+g)*Dn + d] = acc + b_qkv[2*Dn + d];
        }
        __syncthreads();  // O's X-reads complete before next iter's Aq writes
    }
}

//======================= Kernel C: MLP tail (8 batches/block) =============
__global__ __launch_bounds__(256, 2)
void k_tail(const float* __restrict__ q_in, const float* __restrict__ o_ws,
            const float* __restrict__ W_out, const float* __restrict__ b_out,
            const float* __restrict__ ln2_w, const float* __restrict__ ln2_b,
            const float* __restrict__ ln3_w, const float* __restrict__ ln3_b,
            const float* __restrict__ W_ff1, const float* __restrict__ b_ff1,
            const float* __restrict__ ln4_w, const float* __restrict__ ln4_b,
            const float* __restrict__ W_ff2, const float* __restrict__ b_ff2,
            const float* __restrict__ ln5_w, const float* __restrict__ ln5_b,
            const float* __restrict__ W_head, const float* __restrict__ b_head,
            float* __restrict__ out)
{
    const int t    = threadIdx.x;
    const int lane = t & 63;
    const int wv   = t >> 6;
    const int b0   = blockIdx.x * GC;

    __shared__ __align__(16) float s_qi[GC][Dn];
    __shared__ __align__(16) float s_o [GC][Dn];   // o; later h2
    __shared__ __align__(16) float s_t1[GC][Dn];   // t1; later f2h
    __shared__ __align__(16) float s_h [GC][Dn];
    __shared__ __align__(16) float s_l3[GC][Dn];
    __shared__ __align__(16) float s_f1[GC * DFF];

    ((float4*)&s_qi[0][0])[t] = ((const float4*)(q_in + (size_t)b0*Dn))[t];
    ((float4*)&s_o [0][0])[t] = ((const float4*)(o_ws + (size_t)b0*Dn))[t];
    __syncthreads();

    // P6a: t1 = o @ W_out^T + b_out  (group of 128 threads handles 4 batches)
    {
        int d = t & 127, grp = t >> 7;
        const float4* w4 = (const float4*)(W_out + (size_t)d * Dn);
        float acc[4] = {0,0,0,0};
#pragma unroll 8
        for (int j = 0; j < 32; ++j) {
            float4 a = w4[j];
#pragma unroll
            for (int gg = 0; gg < 4; ++gg) {
                float4 v = *(const float4*)&s_o[grp*4 + gg][j*4];
                acc[gg] = fmaf(a.x,v.x,acc[gg]); acc[gg] = fmaf(a.y,v.y,acc[gg]);
                acc[gg] = fmaf(a.z,v.z,acc[gg]); acc[gg] = fmaf(a.w,v.w,acc[gg]);
            }
        }
#pragma unroll
        for (int gg = 0; gg < 4; ++gg) s_t1[grp*4 + gg][d] = acc[gg] + b_out[d];
    }
    __syncthreads();

    // P6b: h = LN(t1, ln2) + q_in  (wave wv handles batches wv and wv+4)
    ln_row64<Dn>(&s_t1[wv][0], &s_h[wv][0], ln2_w, ln2_b, &s_qi[wv][0], lane);
    ln_row64<Dn>(&s_t1[wv+4][0], &s_h[wv+4][0], ln2_w, ln2_b, &s_qi[wv+4][0], lane);
    __syncthreads();
    // P6c: ln3h
    ln_row64<Dn>(&s_h[wv][0], &s_l3[wv][0], ln3_w, ln3_b, nullptr, lane);
    ln_row64<Dn>(&s_h[wv+4][0], &s_l3[wv+4][0], ln3_w, ln3_b, nullptr, lane);
    __syncthreads();

    // P6d: f1 = gelu(ln3h @ W_ff1^T + b_ff1)
    {
        int e0 = t, e1 = t + 256;
        const float4* wa = (const float4*)(W_ff1 + (size_t)e0 * Dn);
        const float4* wb = (const float4*)(W_ff1 + (size_t)e1 * Dn);
        float acc0[GC], acc1[GC];
#pragma unroll
        for (int g = 0; g < GC; ++g) { acc0[g] = 0.f; acc1[g] = 0.f; }
#pragma unroll 2
        for (int j = 0; j < 32; ++j) {
            float4 a = wa[j], bb = wb[j];
#pragma unroll
            for (int g = 0; g < GC; ++g) {
                float4 v = *(const float4*)&s_l3[g][j*4];
                acc0[g] = fmaf(a.x,v.x,acc0[g]);  acc0[g] = fmaf(a.y,v.y,acc0[g]);
                acc0[g] = fmaf(a.z,v.z,acc0[g]);  acc0[g] = fmaf(a.w,v.w,acc0[g]);
                acc1[g] = fmaf(bb.x,v.x,acc1[g]); acc1[g] = fmaf(bb.y,v.y,acc1[g]);
                acc1[g] = fmaf(bb.z,v.z,acc1[g]); acc1[g] = fmaf(bb.w,v.w,acc1[g]);
            }
        }
#pragma unroll
        for (int g = 0; g < GC; ++g) {
            float v0 = acc0[g] + b_ff1[e0];
            float v1 = acc1[g] + b_ff1[e1];
            s_f1[g*DFF + e0] = 0.5f * v0 * (1.f + erff(v0 * INV_SQRT2));
            s_f1[g*DFF + e1] = 0.5f * v1 * (1.f + erff(v1 * INV_SQRT2));
        }
    }
    __syncthreads();

    // P6e: LN(f1, ln4) in place
    ln_row64<DFF>(&s_f1[wv*DFF], &s_f1[wv*DFF], ln4_w, ln4_b, nullptr, lane);
    ln_row64<DFF>(&s_f1[(wv+4)*DFF], &s_f1[(wv+4)*DFF], ln4_w, ln4_b, nullptr, lane);
    __syncthreads();

    // P6f: f2h = f1 @ W_ff2^T + b_ff2 + h -> s_t1 (dead)
    {
        int d = t & 127, grp = t >> 7;
        const float4* w4 = (const float4*)(W_ff2 + (size_t)d * DFF);
        float acc[4] = {0,0,0,0};
#pragma unroll 4
        for (int j = 0; j < DFF/4; ++j) {
            float4 a = w4[j];
#pragma unroll
            for (int gg = 0; gg < 4; ++gg) {
                float4 v = ((const float4*)&s_f1[(grp*4 + gg)*DFF])[j];
                acc[gg] = fmaf(a.x,v.x,acc[gg]); acc[gg] = fmaf(a.y,v.y,acc[gg]);
                acc[gg] = fmaf(a.z,v.z,acc[gg]); acc[gg] = fmaf(a.w,v.w,acc[gg]);
            }
        }
#pragma unroll
        for (int gg = 0; gg < 4; ++gg)
            s_t1[grp*4 + gg][d] = acc[gg] + b_ff2[d] + s_h[grp*4 + gg][d];
    }
    __syncthreads();

    // P6g: h2 = LN(ln5) -> s_o (dead)
    ln_row64<Dn>(&s_t1[wv][0], &s_o[wv][0], ln5_w, ln5_b, nullptr, lane);
    ln_row64<Dn>(&s_t1[wv+4][0], &s_o[wv+4][0], ln5_w, ln5_b, nullptr, lane);
    __syncthreads();

    // P6h: out = h2 @ W_head^T + b_head
    {
        int e0 = t, e1 = t + 256;
        const float4* wa = (const float4*)(W_head + (size_t)e0 * Dn);
        const float4* wb = (const float4*)(W_head + (size_t)e1 * Dn);
        float acc0[GC], acc1[GC];
#pragma unroll
        for (int g = 0; g < GC; ++g) { acc0[g] = 0.f; acc1[g] = 0.f; }
#pragma unroll 2
        for (int j = 0; j < 32; ++j) {
            float4 a = wa[j], bb = wb[j];
#pragma unroll
            for (int g = 0; g < GC; ++g) {
                float4 v = *(const float4*)&s_o[g][j*4];
                acc0[g] = fmaf(a.x,v.x,acc0[g]);  acc0[g] = fmaf(a.y,v.y,acc0[g]);
                acc0[g] = fmaf(a.z,v.z,acc0[g]);  acc0[g] = fmaf(a.w,v.w,acc0[g]);
                acc1[g] = fmaf(bb.x,v.x,acc1[g]); acc1[g] = fmaf(bb.y,v.y,acc1[g]);
                acc1[g] = fmaf(bb.z,v.z,acc1[g]); acc1[g] = fmaf(bb.w,v.w,acc1[g]);
            }
        }
#pragma unroll
        for (int g = 0; g < GC; ++g) {
            out[(size_t)(b0+g)*DIN + e0] = acc0[g] + b_head[e0];
            out[(size_t)(b0+g)*DIN + e1] = acc1[g] + b_head[e1];
        }
    }
}

} // namespace

extern "C" void kernel_launch(void* const* d_in, const int* in_sizes, int n_in,
                              void* d_out, int out_size, void* d_ws, size_t ws_size,
                              hipStream_t stream)
{
    const float* x      = (const float*)d_in[0];
    const float* W_in   = (const float*)d_in[1];
    const float* b_in   = (const float*)d_in[2];
    const float* pos    = (const float*)d_in[3];
    const float* mask   = (const float*)d_in[4];
    const float* mem    = (const float*)d_in[5];
    const float* ln1_w  = (const float*)d_in[6];
    const float* ln1_b  = (const float*)d_in[7];
    const float* W_qkv  = (const float*)d_in[8];
    const float* b_qkv  = (const float*)d_in[9];
    const float* W_out  = (const float*)d_in[10];
    const float* b_out  = (const float*)d_in[11];
    const float* ln2_w  = (const float*)d_in[12];
    const float* ln2_b  = (const float*)d_in[13];
    const float* ln3_w  = (const float*)d_in[14];
    const float* ln3_b  = (const float*)d_in[15];
    const float* W_ff1  = (const float*)d_in[16];
    const float* b_ff1  = (const float*)d_in[17];
    const float* ln4_w  = (const float*)d_in[18];
    const float* ln4_b  = (const float*)d_in[19];
    const float* W_ff2  = (const float*)d_in[20];
    const float* b_ff2  = (const float*)d_in[21];
    const float* ln5_w  = (const float*)d_in[22];
    const float* ln5_b  = (const float*)d_in[23];
    const float* W_head = (const float*)d_in[24];
    const float* b_head = (const float*)d_in[25];

    const int B = in_sizes[0] / DIN;   // 4096
    float* ws_qin = (float*)d_ws;                       // B*128 floats (2 MB)
    float* ws_o   = (float*)d_ws + (size_t)B * Dn;      // B*128 floats (2 MB)

    k_qin<<<dim3(B / 8), dim3(256), 0, stream>>>(x, W_in, b_in, pos, ws_qin);
    k_attn<<<dim3(B / GA), dim3(256), 0, stream>>>(ws_qin, mask, mem,
                                                   ln1_w, ln1_b, W_qkv, b_qkv, ws_o);
    k_tail<<<dim3(B / GC), dim3(256), 0, stream>>>(ws_qin, ws_o,
        W_out, b_out, ln2_w, ln2_b, ln3_w, ln3_b,
        W_ff1, b_ff1, ln4_w, ln4_b, W_ff2, b_ff2,
        ln5_w, ln5_b, W_head, b_head, (float*)d_out);
}

// Round 14
// 254.273 us; speedup vs baseline: 2.1486x; 1.0561x over previous
//
#include <hip/hip_runtime.h>

namespace {

constexpr int Dn   = 128;
constexpr int DIN  = 512;
constexpr int Hn   = 8;
constexpr int Mn   = 128;
constexpr int DFF  = 512;
constexpr int GC   = 8;     // batches per k_tail block
constexpr float ATT_SCALE = 0.25f;
constexpr float INV_SQRT2 = 0.70710678118654752440f;

typedef short  short8v  __attribute__((ext_vector_type(8)));
typedef float  float4v  __attribute__((ext_vector_type(4)));

__device__ __forceinline__ unsigned pk_bf16(float lo, float hi) {
    unsigned r;
    asm volatile("v_cvt_pk_bf16_f32 %0, %1, %2" : "=v"(r) : "v"(lo), "v"(hi));
    return r;
}
__device__ __forceinline__ float lo16(unsigned u) { return __uint_as_float(u << 16); }
__device__ __forceinline__ float hi16(unsigned u) { return __uint_as_float(u & 0xffff0000u); }

__device__ __forceinline__ float dot128(const float* __restrict__ wrow,
                                        const float* __restrict__ v)
{
    const float4* w4 = (const float4*)wrow;
    const float4* v4 = (const float4*)v;
    float acc = 0.f;
#pragma unroll
    for (int j = 0; j < 32; ++j) {
        float4 a = w4[j], b = v4[j];
        acc += a.x*b.x + a.y*b.y + a.z*b.z + a.w*b.w;
    }
    return acc;
}

template <int NCOL>
__device__ __forceinline__ void ln_row64(const float* __restrict__ src,
                                         float* __restrict__ dst,
                                         const float* __restrict__ gw,
                                         const float* __restrict__ gb,
                                         const float* __restrict__ resid,
                                         int sub)
{
    constexpr int E = NCOL / 64;
    float v0[E]; float sm = 0.f;
#pragma unroll
    for (int i = 0; i < E; ++i) { v0[i] = src[sub*E + i]; sm += v0[i]; }
#pragma unroll
    for (int m = 32; m >= 1; m >>= 1) sm += __shfl_xor(sm, m);
    float mean = sm * (1.f / (float)NCOL);
    float vs = 0.f;
#pragma unroll
    for (int i = 0; i < E; ++i) { float d0 = v0[i] - mean; vs += d0*d0; }
#pragma unroll
    for (int m = 32; m >= 1; m >>= 1) vs += __shfl_xor(vs, m);
    float rstd = rsqrtf(vs * (1.f / (float)NCOL) + 1e-5f);
#pragma unroll
    for (int i = 0; i < E; ++i) {
        int d = sub*E + i;
        float r = (v0[i] - mean) * rstd * gw[d] + gb[d];
        dst[d] = resid ? (r + resid[d]) : r;
    }
}

//======================= Kernel A: q_in projection =======================
__global__ __launch_bounds__(256, 2)
void k_qin(const float* __restrict__ x, const float* __restrict__ W_in,
           const float* __restrict__ b_in, const float* __restrict__ pos,
           float* __restrict__ q_in)
{
    const int t  = threadIdx.x;
    const int b0 = blockIdx.x * 8;
    __shared__ __align__(16) float s_x[8 * DIN];
    {
        const float4* src = (const float4*)(x + (size_t)b0 * DIN);
        float4* dst = (float4*)s_x;
#pragma unroll
        for (int i = 0; i < 4; ++i) dst[t + 256*i] = src[t + 256*i];
    }
    __syncthreads();
    {
        int d = t & 127, gq = t >> 7;
        const float4* w4 = (const float4*)(W_in + (size_t)d * DIN);
        float acc[4] = {0,0,0,0};
        for (int j = 0; j < DIN/4; ++j) {
            float4 a = w4[j];
#pragma unroll
            for (int g = 0; g < 4; ++g) {
                float4 xv = ((const float4*)s_x)[(gq*4 + g)*(DIN/4) + j];
                acc[g] = fmaf(a.x, xv.x, acc[g]); acc[g] = fmaf(a.y, xv.y, acc[g]);
                acc[g] = fmaf(a.z, xv.z, acc[g]); acc[g] = fmaf(a.w, xv.w, acc[g]);
            }
        }
#pragma unroll
        for (int g = 0; g < 4; ++g) {
            int gb = b0 + gq*4 + g;
            q_in[(size_t)gb*Dn + d] = acc[g] + b_in[d] + pos[(size_t)gb*Dn + d];
        }
    }
}

//=========== Kernel B: attention (1 batch/block, MFMA dots) — r11 version =
__global__ __launch_bounds__(256, 2)
void k_attn(const float* __restrict__ q_in,
            const float* __restrict__ mask,
            const float* __restrict__ mem,
            const float* __restrict__ ln1_w, const float* __restrict__ ln1_b,
            const float* __restrict__ W_qkv, const float* __restrict__ b_qkv,
            float* __restrict__ o_ws)
{
    const int t    = threadIdx.x;
    const int lane = t & 63;
    const int wv   = t >> 6;
    const int b    = blockIdx.x;

    __shared__ __align__(16) unsigned short s16[Mn * Dn];   // bf16 tile, swizzled (32KB)
    __shared__ __align__(16) float s_X[1312];   // A' -> dots/qw -> ctxn
    __shared__ __align__(16) float s_lnq[Dn];
    __shared__ __align__(16) float s_qi[Dn];
    __shared__ __align__(16) float s_q[Dn];
    __shared__ float s_s2c[Hn], s_s0[Hn], s_den[Hn], s_p0[Hn];

    unsigned short* s_At = (unsigned short*)s_X;   // [16][136] bf16
    float* s_sc = s_X;                             // [128][10] dots/qw

    if (t < 32) ((float4*)s_qi)[t] = ((const float4*)(q_in + (size_t)b*Dn))[t];
    __syncthreads();

    // S: stage tile bf16 chunk-swizzled; wave0 lnq; waves 2-3 q
    {
        const float4* src = (const float4*)(mem + (size_t)b * Mn * Dn);
#pragma unroll
        for (int i = 0; i < 16; ++i) {
            int fid = t + 256*i;
            float4 v = src[fid];
            int r = fid >> 5, k = fid & 31;
            int c = k >> 1, half = k & 1;
            unsigned u0 = pk_bf16(v.x, v.y), u1 = pk_bf16(v.z, v.w);
            *(uint2*)&s16[r*128 + ((c ^ (r & 7)) << 3) + half*4] = make_uint2(u0, u1);
        }
    }
    if (t < 64) {
        ln_row64<Dn>(s_qi, s_lnq, ln1_w, ln1_b, nullptr, t);
    } else if (t >= 128) {
        int dd = t - 128;
        s_q[dd] = dot128(W_qkv + (size_t)dd*Dn, s_qi) + b_qkv[dd];
    }
    __syncthreads();

    // Aq: A' bf16 [16][136] (s1-folded) + zero pad rows + scalars s2c/s0
    {
        int h = t >> 5, js = t & 31;
        float aq[4] = {0,0,0,0};
        float ch = 0.f;
#pragma unroll
        for (int d0 = 0; d0 < 16; ++d0) {
            float qv = s_q[h*16 + d0];
            float4 w = ((const float4*)(W_qkv + (size_t)(Dn + h*16 + d0)*Dn))[js];
            aq[0] = fmaf(qv, w.x, aq[0]); aq[1] = fmaf(qv, w.y, aq[1]);
            aq[2] = fmaf(qv, w.z, aq[2]); aq[3] = fmaf(qv, w.w, aq[3]);
            ch = fmaf(qv, b_qkv[Dn + h*16 + d0], ch);
        }
        ch *= ATT_SCALE;
        float s1p = 0.f, s2p = 0.f, s0p = 0.f;
        float aqw[4];
#pragma unroll
        for (int c = 0; c < 4; ++c) {
            int j = js*4 + c;
            float a = ATT_SCALE * aq[c];
            aqw[c] = a * ln1_w[j];
            s1p += aqw[c];
            s2p = fmaf(a, ln1_b[j], s2p);
            s0p = fmaf(a, s_lnq[j], s0p);
        }
#pragma unroll
        for (int m = 16; m >= 1; m >>= 1) {
            s1p += __shfl_xor(s1p, m, 32);
            s2p += __shfl_xor(s2p, m, 32);
            s0p += __shfl_xor(s0p, m, 32);
        }
        float sub = s1p * (1.f/128.f);
        *(unsigned*)&s_At[h*136 + 4*js]     = pk_bf16(aqw[0]-sub, aqw[1]-sub);
        *(unsigned*)&s_At[h*136 + 4*js + 2] = pk_bf16(aqw[2]-sub, aqw[3]-sub);
        if (js == 0) { s_s2c[h] = s2p + ch; s_s0[h] = s0p + ch; }
        unsigned* X32 = (unsigned*)s_At;
        for (int idx = t; idx < 544; idx += 256) X32[8*68 + idx] = 0;
    }
    __syncthreads();

    // Pass A: MFMA dots  D[16h][128r] = A'[16][128] x tile^T  + VALU row stats
    float4v acc0 = {0.f,0.f,0.f,0.f}, acc1 = {0.f,0.f,0.f,0.f};
    float rstd_reg = 0.f;
    {
        const int al = lane & 15, ag = lane >> 4;
        const int r0 = (2*wv)*16 + al, r1 = (2*wv+1)*16 + al;
#pragma unroll
        for (int ks = 0; ks < 4; ++ks) {
            short8v af = *(const short8v*)&s_At[al*136 + ks*32 + ag*8];
            int c = ks*4 + ag;
            short8v b0 = *(const short8v*)&s16[r0*128 + ((c ^ (r0 & 7)) << 3)];
            short8v b1 = *(const short8v*)&s16[r1*128 + ((c ^ (r1 & 7)) << 3)];
            acc0 = __builtin_amdgcn_mfma_f32_16x16x32_bf16(af, b0, acc0, 0, 0, 0);
            acc1 = __builtin_amdgcn_mfma_f32_16x16x32_bf16(af, b1, acc1, 0, 0, 0);
        }
        int r = t >> 1, hf = t & 1;
        float sum = 0.f, ssq = 0.f;
#pragma unroll
        for (int kk = 0; kk < 8; ++kk) {
            int c = hf*8 + kk;
            uint4 tv = *(const uint4*)&s16[r*128 + ((c ^ (r & 7)) << 3)];
            float vv[8];
            vv[0] = lo16(tv.x); vv[1] = hi16(tv.x);
            vv[2] = lo16(tv.y); vv[3] = hi16(tv.y);
            vv[4] = lo16(tv.z); vv[5] = hi16(tv.z);
            vv[6] = lo16(tv.w); vv[7] = hi16(tv.w);
#pragma unroll
            for (int q = 0; q < 8; ++q) { sum += vv[q]; ssq = fmaf(vv[q], vv[q], ssq); }
        }
        sum += __shfl_xor(sum, 1);
        ssq += __shfl_xor(ssq, 1);
        float mean = sum * (1.f/128.f);
        float var  = fmaf(-mean, mean, ssq * (1.f/128.f));
        rstd_reg = rsqrtf(var + 1e-5f);
    }
    __syncthreads();   // all A' reads done; region X switches to dots

    // W: write dots (lanes 0-31: heads 0-7) + rstd
    {
        if (lane < 32) {
            int al = lane & 15, hb = (lane >> 4) * 4;
            int r0 = (2*wv)*16 + al, r1 = (2*wv+1)*16 + al;
#pragma unroll
            for (int reg = 0; reg < 4; ++reg) {
                s_sc[r0*10 + hb + reg] = acc0[reg];
                s_sc[r1*10 + hb + reg] = acc1[reg];
            }
        }
        if ((t & 1) == 0) s_sc[(t >> 1)*10 + 8] = rstd_reg;
    }
    __syncthreads();

    // SM: one-shot softmax; wave w -> heads 2w,2w+1; lane l -> rows 2l,2l+1
    {
        int w = wv, l = lane;
        int h0 = 2*w, h1 = h0 + 1;
        int r0 = 2*l, r1 = r0 + 1;
        float2 da = *(const float2*)&s_sc[r0*10 + h0];
        float2 db = *(const float2*)&s_sc[r1*10 + h0];
        float rs0 = s_sc[r0*10 + 8], rs1 = s_sc[r1*10 + 8];
        float2 mk = *(const float2*)&mask[(size_t)b*Mn + r0];
        float sc00 = fmaf(rs0, da.x, s_s2c[h0]) + mk.x;
        float sc01 = fmaf(rs0, da.y, s_s2c[h1]) + mk.x;
        float sc10 = fmaf(rs1, db.x, s_s2c[h0]) + mk.y;
        float sc11 = fmaf(rs1, db.y, s_s2c[h1]) + mk.y;
        float mx0 = fmaxf(sc00, sc10), mx1 = fmaxf(sc01, sc11);
#pragma unroll
        for (int m = 1; m < 64; m <<= 1) {
            mx0 = fmaxf(mx0, __shfl_xor(mx0, m));
            mx1 = fmaxf(mx1, __shfl_xor(mx1, m));
        }
        mx0 = fmaxf(mx0, s_s0[h0]);
        mx1 = fmaxf(mx1, s_s0[h1]);
        float e00 = __expf(sc00 - mx0), e10 = __expf(sc10 - mx0);
        float e01 = __expf(sc01 - mx1), e11 = __expf(sc11 - mx1);
        float ds0 = e00 + e10, ds1 = e01 + e11;
#pragma unroll
        for (int m = 1; m < 64; m <<= 1) {
            ds0 += __shfl_xor(ds0, m);
            ds1 += __shfl_xor(ds1, m);
        }
        float p00 = __expf(s_s0[h0] - mx0), p01 = __expf(s_s0[h1] - mx1);
        *(float2*)&s_sc[r0*10 + h0] = make_float2(e00*rs0, e01*rs0);
        *(float2*)&s_sc[r1*10 + h0] = make_float2(e10*rs1, e11*rs1);
        if (l == 0) {
            s_den[h0] = ds0 + p00; s_p0[h0] = p00;
            s_den[h1] = ds1 + p01; s_p0[h1] = p01;
        }
    }
    __syncthreads();

    // C: ctx (wave = head pair; quarter = 32 rows; lane chunk = 8 cols)
    float cx0[8], cx1[8], cS0, cS1;
    {
        int w = wv, l = lane;
        int qtr = l >> 4, c = l & 15;
#pragma unroll
        for (int q = 0; q < 8; ++q) { cx0[q] = 0.f; cx1[q] = 0.f; }
#pragma unroll 4
        for (int rr = 0; rr < 32; ++rr) {
            int r = qtr*32 + rr;
            uint4 tv = *(const uint4*)&s16[r*128 + ((c ^ (r & 7)) << 3)];
            float2 qv = *(const float2*)&s_sc[r*10 + 2*w];
            float v0 = lo16(tv.x), v1 = hi16(tv.x);
            float v2 = lo16(tv.y), v3 = hi16(tv.y);
            float v4 = lo16(tv.z), v5 = hi16(tv.z);
            float v6 = lo16(tv.w), v7 = hi16(tv.w);
            cx0[0]=fmaf(qv.x,v0,cx0[0]); cx1[0]=fmaf(qv.y,v0,cx1[0]);
            cx0[1]=fmaf(qv.x,v1,cx0[1]); cx1[1]=fmaf(qv.y,v1,cx1[1]);
            cx0[2]=fmaf(qv.x,v2,cx0[2]); cx1[2]=fmaf(qv.y,v2,cx1[2]);
            cx0[3]=fmaf(qv.x,v3,cx0[3]); cx1[3]=fmaf(qv.y,v3,cx1[3]);
            cx0[4]=fmaf(qv.x,v4,cx0[4]); cx1[4]=fmaf(qv.y,v4,cx1[4]);
            cx0[5]=fmaf(qv.x,v5,cx0[5]); cx1[5]=fmaf(qv.y,v5,cx1[5]);
            cx0[6]=fmaf(qv.x,v6,cx0[6]); cx1[6]=fmaf(qv.y,v6,cx1[6]);
            cx0[7]=fmaf(qv.x,v7,cx0[7]); cx1[7]=fmaf(qv.y,v7,cx1[7]);
        }
#pragma unroll
        for (int q = 0; q < 8; ++q) {
            cx0[q] += __shfl_xor(cx0[q], 16);
            cx0[q] += __shfl_xor(cx0[q], 32);
            cx1[q] += __shfl_xor(cx1[q], 16);
            cx1[q] += __shfl_xor(cx1[q], 32);
        }
        float sA = ((cx0[0]+cx0[1])+(cx0[2]+cx0[3])) + ((cx0[4]+cx0[5])+(cx0[6]+cx0[7]));
        float sB = ((cx1[0]+cx1[1])+(cx1[2]+cx1[3])) + ((cx1[4]+cx1[5])+(cx1[6]+cx1[7]));
#pragma unroll
        for (int m = 1; m < 16; m <<= 1) {
            sA += __shfl_xor(sA, m);
            sB += __shfl_xor(sB, m);
        }
        cS0 = sA * (1.f/128.f);
        cS1 = sB * (1.f/128.f);
    }
    __syncthreads();   // qw reads done before ctxn overwrites s_X

    // D: verified fold -> ctxn[8][128] into region X
    if (lane < 16) {
        int c = lane;
        int h0 = 2*wv, h1 = h0 + 1;
        float den0 = s_den[h0], p0a = s_p0[h0], sP0 = den0 - p0a, inv0 = 1.f/den0;
        float den1 = s_den[h1], p0b = s_p0[h1], sP1 = den1 - p0b, inv1 = 1.f/den1;
#pragma unroll
        for (int q = 0; q < 2; ++q) {
            int j0 = c*8 + q*4;
            float4 lq = *(const float4*)&s_lnq[j0];
            float4 lw = *(const float4*)&ln1_w[j0];
            float4 lb = *(const float4*)&ln1_b[j0];
            float4 o0, o1;
            o0.x = (p0a*lq.x + lw.x*(cx0[q*4+0]-cS0) + lb.x*sP0) * inv0;
            o0.y = (p0a*lq.y + lw.y*(cx0[q*4+1]-cS0) + lb.y*sP0) * inv0;
            o0.z = (p0a*lq.z + lw.z*(cx0[q*4+2]-cS0) + lb.z*sP0) * inv0;
            o0.w = (p0a*lq.w + lw.w*(cx0[q*4+3]-cS0) + lb.w*sP0) * inv0;
            o1.x = (p0b*lq.x + lw.x*(cx1[q*4+0]-cS1) + lb.x*sP1) * inv1;
            o1.y = (p0b*lq.y + lw.y*(cx1[q*4+1]-cS1) + lb.y*sP1) * inv1;
            o1.z = (p0b*lq.z + lw.z*(cx1[q*4+2]-cS1) + lb.z*sP1) * inv1;
            o1.w = (p0b*lq.w + lw.w*(cx1[q*4+3]-cS1) + lb.w*sP1) * inv1;
            *(float4*)&s_X[h0*128 + j0] = o0;
            *(float4*)&s_X[h1*128 + j0] = o1;
        }
    }
    __syncthreads();

    // O: o = Wv @ ctxn + bv  (2 threads/output, K-split 64/64)
    {
        int d = t >> 1, half = t & 1;
        int h = d >> 4;
        const float4* w4 = (const float4*)(W_qkv + (size_t)(2*Dn + d)*Dn) + half*16;
        const float4* c4 = (const float4*)&s_X[h*128] + half*16;
        float acc = 0.f;
#pragma unroll
        for (int j = 0; j < 16; ++j) {
            float4 a = w4[j], v = c4[j];
            acc += a.x*v.x + a.y*v.y + a.z*v.z + a.w*v.w;
        }
        acc += __shfl_xor(acc, 1);
        if (half == 0)
            o_ws[(size_t)b*Dn + d] = acc + b_qkv[2*Dn + d];
    }
}

//======================= Kernel C: MLP tail (8 batches/block) =============
__global__ __launch_bounds__(256, 2)
void k_tail(const float* __restrict__ q_in, const float* __restrict__ o_ws,
            const float* __restrict__ W_out, const float* __restrict__ b_out,
            const float* __restrict__ ln2_w, const float* __restrict__ ln2_b,
            const float* __restrict__ ln3_w, const float* __restrict__ ln3_b,
            const float* __restrict__ W_ff1, const float* __restrict__ b_ff1,
            const float* __restrict__ ln4_w, const float* __restrict__ ln4_b,
            const float* __restrict__ W_ff2, const float* __restrict__ b_ff2,
            const float* __restrict__ ln5_w, const float* __restrict__ ln5_b,
            const float* __restrict__ W_head, const float* __restrict__ b_head,
            float* __restrict__ out)
{
    const int t    = threadIdx.x;
    const int lane = t & 63;
    const int wv   = t >> 6;
    const int b0   = blockIdx.x * GC;

    __shared__ __align__(16) float s_qi[GC][Dn];
    __shared__ __align__(16) float s_o [GC][Dn];   // o; later h2
    __shared__ __align__(16) float s_t1[GC][Dn];   // t1; later f2h
    __shared__ __align__(16) float s_h [GC][Dn];
    __shared__ __align__(16) float s_l3[GC][Dn];
    __shared__ __align__(16) float s_f1[GC * DFF];

    ((float4*)&s_qi[0][0])[t] = ((const float4*)(q_in + (size_t)b0*Dn))[t];
    ((float4*)&s_o [0][0])[t] = ((const float4*)(o_ws + (size_t)b0*Dn))[t];
    __syncthreads();

    // P6a: t1 = o @ W_out^T + b_out
    {
        int d = t & 127, grp = t >> 7;
        const float4* w4 = (const float4*)(W_out + (size_t)d * Dn);
        float acc[4] = {0,0,0,0};
#pragma unroll 8
        for (int j = 0; j < 32; ++j) {
            float4 a = w4[j];
#pragma unroll
            for (int gg = 0; gg < 4; ++gg) {
                float4 v = *(const float4*)&s_o[grp*4 + gg][j*4];
                acc[gg] = fmaf(a.x,v.x,acc[gg]); acc[gg] = fmaf(a.y,v.y,acc[gg]);
                acc[gg] = fmaf(a.z,v.z,acc[gg]); acc[gg] = fmaf(a.w,v.w,acc[gg]);
            }
        }
#pragma unroll
        for (int gg = 0; gg < 4; ++gg) s_t1[grp*4 + gg][d] = acc[gg] + b_out[d];
    }
    __syncthreads();

    // P6b: h = LN(t1, ln2) + q_in  (wave wv handles batches wv and wv+4)
    ln_row64<Dn>(&s_t1[wv][0], &s_h[wv][0], ln2_w, ln2_b, &s_qi[wv][0], lane);
    ln_row64<Dn>(&s_t1[wv+4][0], &s_h[wv+4][0], ln2_w, ln2_b, &s_qi[wv+4][0], lane);
    __syncthreads();
    // P6c: ln3h
    ln_row64<Dn>(&s_h[wv][0], &s_l3[wv][0], ln3_w, ln3_b, nullptr, lane);
    ln_row64<Dn>(&s_h[wv+4][0], &s_l3[wv+4][0], ln3_w, ln3_b, nullptr, lane);
    __syncthreads();

    // P6d: f1 = gelu(ln3h @ W_ff1^T + b_ff1)
    {
        int e0 = t, e1 = t + 256;
        const float4* wa = (const float4*)(W_ff1 + (size_t)e0 * Dn);
        const float4* wb = (const float4*)(W_ff1 + (size_t)e1 * Dn);
        float acc0[GC], acc1[GC];
#pragma unroll
        for (int g = 0; g < GC; ++g) { acc0[g] = 0.f; acc1[g] = 0.f; }
#pragma unroll 2
        for (int j = 0; j < 32; ++j) {
            float4 a = wa[j], bb = wb[j];
#pragma unroll
            for (int g = 0; g < GC; ++g) {
                float4 v = *(const float4*)&s_l3[g][j*4];
                acc0[g] = fmaf(a.x,v.x,acc0[g]);  acc0[g] = fmaf(a.y,v.y,acc0[g]);
                acc0[g] = fmaf(a.z,v.z,acc0[g]);  acc0[g] = fmaf(a.w,v.w,acc0[g]);
                acc1[g] = fmaf(bb.x,v.x,acc1[g]); acc1[g] = fmaf(bb.y,v.y,acc1[g]);
                acc1[g] = fmaf(bb.z,v.z,acc1[g]); acc1[g] = fmaf(bb.w,v.w,acc1[g]);
            }
        }
#pragma unroll
        for (int g = 0; g < GC; ++g) {
            float v0 = acc0[g] + b_ff1[e0];
            float v1 = acc1[g] + b_ff1[e1];
            s_f1[g*DFF + e0] = 0.5f * v0 * (1.f + erff(v0 * INV_SQRT2));
            s_f1[g*DFF + e1] = 0.5f * v1 * (1.f + erff(v1 * INV_SQRT2));
        }
    }
    __syncthreads();

    // P6e: LN(f1, ln4) in place
    ln_row64<DFF>(&s_f1[wv*DFF], &s_f1[wv*DFF], ln4_w, ln4_b, nullptr, lane);
    ln_row64<DFF>(&s_f1[(wv+4)*DFF], &s_f1[(wv+4)*DFF], ln4_w, ln4_b, nullptr, lane);
    __syncthreads();

    // P6f: f2h = f1 @ W_ff2^T + b_ff2 + h -> s_t1 (dead)
    {
        int d = t & 127, grp = t >> 7;
        const float4* w4 = (const float4*)(W_ff2 + (size_t)d * DFF);
        float acc[4] = {0,0,0,0};
#pragma unroll 4
        for (int j = 0; j < DFF/4; ++j) {
            float4 a = w4[j];
#pragma unroll
            for (int gg = 0; gg < 4; ++gg) {
                float4 v = ((const float4*)&s_f1[(grp*4 + gg)*DFF])[j];
                acc[gg] = fmaf(a.x,v.x,acc[gg]); acc[gg] = fmaf(a.y,v.y,acc[gg]);
                acc[gg] = fmaf(a.z,v.z,acc[gg]); acc[gg] = fmaf(a.w,v.w,acc[gg]);
            }
        }
#pragma unroll
        for (int gg = 0; gg < 4; ++gg)
            s_t1[grp*4 + gg][d] = acc[gg] + b_ff2[d] + s_h[grp*4 + gg][d];
    }
    __syncthreads();

    // P6g: h2 = LN(ln5) -> s_o (dead)
    ln_row64<Dn>(&s_t1[wv][0], &s_o[wv][0], ln5_w, ln5_b, nullptr, lane);
    ln_row64<Dn>(&s_t1[wv+4][0], &s_o[wv+4][0], ln5_w, ln5_b, nullptr, lane);
    __syncthreads();

    // P6h: out = h2 @ W_head^T + b_head
    {
        int e0 = t, e1 = t + 256;
        const float4* wa = (const float4*)(W_head + (size_t)e0 * Dn);
        const float4* wb = (const float4*)(W_head + (size_t)e1 * Dn);
        float acc0[GC], acc1[GC];
#pragma unroll
        for (int g = 0; g < GC; ++g) { acc0[g] = 0.f; acc1[g] = 0.f; }
#pragma unroll 2
        for (int j = 0; j < 32; ++j) {
            float4 a = wa[j], bb = wb[j];
#pragma unroll
            for (int g = 0; g < GC; ++g) {
                float4 v = *(const float4*)&s_o[g][j*4];
                acc0[g] = fmaf(a.x,v.x,acc0[g]);  acc0[g] = fmaf(a.y,v.y,acc0[g]);
                acc0[g] = fmaf(a.z,v.z,acc0[g]);  acc0[g] = fmaf(a.w,v.w,acc0[g]);
                acc1[g] = fmaf(bb.x,v.x,acc1[g]); acc1[g] = fmaf(bb.y,v.y,acc1[g]);
                acc1[g] = fmaf(bb.z,v.z,acc1[g]); acc1[g] = fmaf(bb.w,v.w,acc1[g]);
            }
        }
#pragma unroll
        for (int g = 0; g < GC; ++g) {
            out[(size_t)(b0+g)*DIN + e0] = acc0[g] + b_head[e0];
            out[(size_t)(b0+g)*DIN + e1] = acc1[g] + b_head[e1];
        }
    }
}

} // namespace

extern "C" void kernel_launch(void* const* d_in, const int* in_sizes, int n_in,
                              void* d_out, int out_size, void* d_ws, size_t ws_size,
                              hipStream_t stream)
{
    const float* x      = (const float*)d_in[0];
    const float* W_in   = (const float*)d_in[1];
    const float* b_in   = (const float*)d_in[2];
    const float* pos    = (const float*)d_in[3];
    const float* mask   = (const float*)d_in[4];
    const float* mem    = (const float*)d_in[5];
    const float* ln1_w  = (const float*)d_in[6];
    const float* ln1_b  = (const float*)d_in[7];
    const float* W_qkv  = (const float*)d_in[8];
    const float* b_qkv  = (const float*)d_in[9];
    const float* W_out  = (const float*)d_in[10];
    const float* b_out  = (const float*)d_in[11];
    const float* ln2_w  = (const float*)d_in[12];
    const float* ln2_b  = (const float*)d_in[13];
    const float* ln3_w  = (const float*)d_in[14];
    const float* ln3_b  = (const float*)d_in[15];
    const float* W_ff1  = (const float*)d_in[16];
    const float* b_ff1  = (const float*)d_in[17];
    const float* ln4_w  = (const float*)d_in[18];
    const float* ln4_b  = (const float*)d_in[19];
    const float* W_ff2  = (const float*)d_in[20];
    const float* b_ff2  = (const float*)d_in[21];
    const float* ln5_w  = (const float*)d_in[22];
    const float* ln5_b  = (const float*)d_in[23];
    const float* W_head = (const float*)d_in[24];
    const float* b_head = (const float*)d_in[25];

    const int B = in_sizes[0] / DIN;   // 4096
    float* ws_qin = (float*)d_ws;                       // B*128 floats (2 MB)
    float* ws_o   = (float*)d_ws + (size_t)B * Dn;      // B*128 floats (2 MB)

    k_qin<<<dim3(B / 8), dim3(256), 0, stream>>>(x, W_in, b_in, pos, ws_qin);
    k_attn<<<dim3(B), dim3(256), 0, stream>>>(ws_qin, mask, mem,
                                              ln1_w, ln1_b, W_qkv, b_qkv, ws_o);
    k_tail<<<dim3(B / GC), dim3(256), 0, stream>>>(ws_qin, ws_o,
        W_out, b_out, ln2_w, ln2_b, ln3_w, ln3_b,
        W_ff1, b_ff1, ln4_w, ln4_b, W_ff2, b_ff2,
        ln5_w, ln5_b, W_head, b_head, (float*)d_out);
}

// Round 15
// 241.967 us; speedup vs baseline: 2.2579x; 1.0509x over previous
//
#include <hip/hip_runtime.h>

namespace {

constexpr int Dn   = 128;
constexpr int DIN  = 512;
constexpr int Hn   = 8;
constexpr int Mn   = 128;
constexpr int DFF  = 512;
constexpr int GC   = 8;     // batches per k_tail block
constexpr float ATT_SCALE = 0.25f;
constexpr float INV_SQRT2 = 0.70710678118654752440f;

typedef short  short8v  __attribute__((ext_vector_type(8)));
typedef float  float4v  __attribute__((ext_vector_type(4)));

__device__ __forceinline__ unsigned pk_bf16(float lo, float hi) {
    unsigned r;
    asm volatile("v_cvt_pk_bf16_f32 %0, %1, %2" : "=v"(r) : "v"(lo), "v"(hi));
    return r;
}
__device__ __forceinline__ float lo16(unsigned u) { return __uint_as_float(u << 16); }
__device__ __forceinline__ float hi16(unsigned u) { return __uint_as_float(u & 0xffff0000u); }

__device__ __forceinline__ float dot128(const float* __restrict__ wrow,
                                        const float* __restrict__ v)
{
    const float4* w4 = (const float4*)wrow;
    const float4* v4 = (const float4*)v;
    float acc = 0.f;
#pragma unroll
    for (int j = 0; j < 32; ++j) {
        float4 a = w4[j], b = v4[j];
        acc += a.x*b.x + a.y*b.y + a.z*b.z + a.w*b.w;
    }
    return acc;
}

template <int NCOL>
__device__ __forceinline__ void ln_row64(const float* __restrict__ src,
                                         float* __restrict__ dst,
                                         const float* __restrict__ gw,
                                         const float* __restrict__ gb,
                                         const float* __restrict__ resid,
                                         int sub)
{
    constexpr int E = NCOL / 64;
    float v0[E]; float sm = 0.f;
#pragma unroll
    for (int i = 0; i < E; ++i) { v0[i] = src[sub*E + i]; sm += v0[i]; }
#pragma unroll
    for (int m = 32; m >= 1; m >>= 1) sm += __shfl_xor(sm, m);
    float mean = sm * (1.f / (float)NCOL);
    float vs = 0.f;
#pragma unroll
    for (int i = 0; i < E; ++i) { float d0 = v0[i] - mean; vs += d0*d0; }
#pragma unroll
    for (int m = 32; m >= 1; m >>= 1) vs += __shfl_xor(vs, m);
    float rstd = rsqrtf(vs * (1.f / (float)NCOL) + 1e-5f);
#pragma unroll
    for (int i = 0; i < E; ++i) {
        int d = sub*E + i;
        float r = (v0[i] - mean) * rstd * gw[d] + gb[d];
        dst[d] = resid ? (r + resid[d]) : r;
    }
}

//======================= Kernel A: q_in projection =======================
__global__ __launch_bounds__(256, 2)
void k_qin(const float* __restrict__ x, const float* __restrict__ W_in,
           const float* __restrict__ b_in, const float* __restrict__ pos,
           float* __restrict__ q_in)
{
    const int t  = threadIdx.x;
    const int b0 = blockIdx.x * 8;
    __shared__ __align__(16) float s_x[8 * DIN];
    {
        const float4* src = (const float4*)(x + (size_t)b0 * DIN);
        float4* dst = (float4*)s_x;
#pragma unroll
        for (int i = 0; i < 4; ++i) dst[t + 256*i] = src[t + 256*i];
    }
    __syncthreads();
    {
        int d = t & 127, gq = t >> 7;
        const float4* w4 = (const float4*)(W_in + (size_t)d * DIN);
        float acc[4] = {0,0,0,0};
        for (int j = 0; j < DIN/4; ++j) {
            float4 a = w4[j];
#pragma unroll
            for (int g = 0; g < 4; ++g) {
                float4 xv = ((const float4*)s_x)[(gq*4 + g)*(DIN/4) + j];
                acc[g] = fmaf(a.x, xv.x, acc[g]); acc[g] = fmaf(a.y, xv.y, acc[g]);
                acc[g] = fmaf(a.z, xv.z, acc[g]); acc[g] = fmaf(a.w, xv.w, acc[g]);
            }
        }
#pragma unroll
        for (int g = 0; g < 4; ++g) {
            int gb = b0 + gq*4 + g;
            q_in[(size_t)gb*Dn + d] = acc[g] + b_in[d] + pos[(size_t)gb*Dn + d];
        }
    }
}

//=========== Kernel B: attention (1 batch/block, 512 threads, MFMA) =======
__global__ __launch_bounds__(512, 2)
void k_attn(const float* __restrict__ q_in,
            const float* __restrict__ mask,
            const float* __restrict__ mem,
            const float* __restrict__ ln1_w, const float* __restrict__ ln1_b,
            const float* __restrict__ W_qkv, const float* __restrict__ b_qkv,
            float* __restrict__ o_ws)
{
    const int t    = threadIdx.x;
    const int lane = t & 63;
    const int wv   = t >> 6;          // 0..7
    const int b    = blockIdx.x;

    __shared__ __align__(16) unsigned short s16[Mn * Dn];   // bf16 tile, swizzled (32KB)
    __shared__ __align__(16) float s_X[1312];   // A' -> dots/qw -> ctxn
    __shared__ __align__(16) float s_lnq[Dn];
    __shared__ __align__(16) float s_qi[Dn];
    __shared__ __align__(16) float s_q[Dn];
    __shared__ float s_s2c[Hn], s_s0[Hn], s_den[Hn], s_p0[Hn];

    unsigned short* s_At = (unsigned short*)s_X;   // [16][136] bf16
    float* s_sc = s_X;                             // [128][10] dots/qw

    if (t < 32) ((float4*)s_qi)[t] = ((const float4*)(q_in + (size_t)b*Dn))[t];
    __syncthreads();

    // S: stage tile bf16 chunk-swizzled (8 float4/thread); wave0 lnq; waves 2-3 q
    {
        const float4* src = (const float4*)(mem + (size_t)b * Mn * Dn);
#pragma unroll
        for (int i = 0; i < 8; ++i) {
            int fid = t + 512*i;
            float4 v = src[fid];
            int r = fid >> 5, k = fid & 31;
            int c = k >> 1, half = k & 1;
            unsigned u0 = pk_bf16(v.x, v.y), u1 = pk_bf16(v.z, v.w);
            *(uint2*)&s16[r*128 + ((c ^ (r & 7)) << 3) + half*4] = make_uint2(u0, u1);
        }
    }
    if (t < 64) {
        ln_row64<Dn>(s_qi, s_lnq, ln1_w, ln1_b, nullptr, t);
    } else if (t >= 128 && t < 256) {           // 512-thread port: bound the guard!
        int dd = t - 128;
        s_q[dd] = dot128(W_qkv + (size_t)dd*Dn, s_qi) + b_qkv[dd];
    }
    __syncthreads();

    // Aq: wave = head; lane handles cols 2l, 2l+1. A' bf16 [16][136], s1-folded.
    {
        int h = wv, l = lane;
        float aq0 = 0.f, aq1 = 0.f, ch = 0.f;
#pragma unroll
        for (int d0 = 0; d0 < 16; ++d0) {
            float qv = s_q[h*16 + d0];
            float2 w2 = *(const float2*)&W_qkv[(size_t)(Dn + h*16 + d0)*Dn + 2*l];
            aq0 = fmaf(qv, w2.x, aq0);
            aq1 = fmaf(qv, w2.y, aq1);
            ch  = fmaf(qv, b_qkv[Dn + h*16 + d0], ch);
        }
        ch *= ATT_SCALE;
        float a0 = ATT_SCALE * aq0, a1 = ATT_SCALE * aq1;
        float2 lw = *(const float2*)&ln1_w[2*l];
        float2 lb = *(const float2*)&ln1_b[2*l];
        float2 lq = *(const float2*)&s_lnq[2*l];
        float aqw0 = a0 * lw.x, aqw1 = a1 * lw.y;
        float s1p = aqw0 + aqw1;
        float s2p = a0*lb.x + a1*lb.y;
        float s0p = a0*lq.x + a1*lq.y;
#pragma unroll
        for (int m = 32; m >= 1; m >>= 1) {
            s1p += __shfl_xor(s1p, m);
            s2p += __shfl_xor(s2p, m);
            s0p += __shfl_xor(s0p, m);
        }
        float sub = s1p * (1.f/128.f);
        *(unsigned*)&s_At[h*136 + 2*l] = pk_bf16(aqw0 - sub, aqw1 - sub);
        if (l == 0) { s_s2c[h] = s2p + ch; s_s0[h] = s0p + ch; }
        // zero A' rows 8-15 (544 dwords)
        unsigned* X32 = (unsigned*)s_At;
        for (int idx = t; idx < 544; idx += 512) X32[8*68 + idx] = 0;
    }
    __syncthreads();

    // Pass A: MFMA dots (wave wv -> rows wv*16..wv*16+15) + VALU row stats
    float4v acc0 = {0.f,0.f,0.f,0.f};
    float rstd_reg = 0.f;
    {
        const int al = lane & 15, ag = lane >> 4;
        const int r0 = wv*16 + al;
#pragma unroll
        for (int ks = 0; ks < 4; ++ks) {
            short8v af = *(const short8v*)&s_At[al*136 + ks*32 + ag*8];
            int c = ks*4 + ag;
            short8v b0 = *(const short8v*)&s16[r0*128 + ((c ^ (r0 & 7)) << 3)];
            acc0 = __builtin_amdgcn_mfma_f32_16x16x32_bf16(af, b0, acc0, 0, 0, 0);
        }
        // stats: 4 threads/row
        int r = t >> 2, hf = t & 3;
        float sum = 0.f, ssq = 0.f;
#pragma unroll
        for (int kk = 0; kk < 4; ++kk) {
            int c = hf*4 + kk;
            uint4 tv = *(const uint4*)&s16[r*128 + ((c ^ (r & 7)) << 3)];
            float vv[8];
            vv[0] = lo16(tv.x); vv[1] = hi16(tv.x);
            vv[2] = lo16(tv.y); vv[3] = hi16(tv.y);
            vv[4] = lo16(tv.z); vv[5] = hi16(tv.z);
            vv[6] = lo16(tv.w); vv[7] = hi16(tv.w);
#pragma unroll
            for (int q = 0; q < 8; ++q) { sum += vv[q]; ssq = fmaf(vv[q], vv[q], ssq); }
        }
        sum += __shfl_xor(sum, 1); sum += __shfl_xor(sum, 2);
        ssq += __shfl_xor(ssq, 1); ssq += __shfl_xor(ssq, 2);
        float mean = sum * (1.f/128.f);
        float var  = fmaf(-mean, mean, ssq * (1.f/128.f));
        rstd_reg = rsqrtf(var + 1e-5f);
    }
    __syncthreads();   // all A' reads done; region X switches to dots

    // Wdots: lanes 0-31 of each wave write its 16 rows x 8 heads; rstd by stats owner
    {
        if (lane < 32) {
            int al = lane & 15, hb = (lane >> 4) * 4;
            int r0 = wv*16 + al;
#pragma unroll
            for (int reg = 0; reg < 4; ++reg)
                s_sc[r0*10 + hb + reg] = acc0[reg];
        }
        if ((t & 3) == 0) s_sc[(t >> 2)*10 + 8] = rstd_reg;
    }
    __syncthreads();

    // SM: wave = head; lane l -> rows 2l, 2l+1
    {
        int w = wv, l = lane;
        int r0 = 2*l, r1 = r0 + 1;
        float d0 = s_sc[r0*10 + w], rs0 = s_sc[r0*10 + 8];
        float d1 = s_sc[r1*10 + w], rs1 = s_sc[r1*10 + 8];
        float2 mk = *(const float2*)&mask[(size_t)b*Mn + r0];
        float sc0 = fmaf(rs0, d0, s_s2c[w]) + mk.x;
        float sc1 = fmaf(rs1, d1, s_s2c[w]) + mk.y;
        float mx = fmaxf(sc0, sc1);
#pragma unroll
        for (int m = 1; m < 64; m <<= 1) mx = fmaxf(mx, __shfl_xor(mx, m));
        mx = fmaxf(mx, s_s0[w]);
        float e0 = __expf(sc0 - mx), e1 = __expf(sc1 - mx);
        float ds = e0 + e1;
#pragma unroll
        for (int m = 1; m < 64; m <<= 1) ds += __shfl_xor(ds, m);
        float p0 = __expf(s_s0[w] - mx);
        s_sc[r0*10 + w] = e0 * rs0;
        s_sc[r1*10 + w] = e1 * rs1;
        if (l == 0) { s_den[w] = ds + p0; s_p0[w] = p0; }
    }
    __syncthreads();

    // C: wave = head; quarter = 32 rows; lane chunk = 8 cols
    float cx[8], cS;
    {
        int w = wv, l = lane;
        int qtr = l >> 4, c = l & 15;
#pragma unroll
        for (int q = 0; q < 8; ++q) cx[q] = 0.f;
#pragma unroll 4
        for (int rr = 0; rr < 32; ++rr) {
            int r = qtr*32 + rr;
            uint4 tv = *(const uint4*)&s16[r*128 + ((c ^ (r & 7)) << 3)];
            float qv = s_sc[r*10 + w];
            cx[0] = fmaf(qv, lo16(tv.x), cx[0]);
            cx[1] = fmaf(qv, hi16(tv.x), cx[1]);
            cx[2] = fmaf(qv, lo16(tv.y), cx[2]);
            cx[3] = fmaf(qv, hi16(tv.y), cx[3]);
            cx[4] = fmaf(qv, lo16(tv.z), cx[4]);
            cx[5] = fmaf(qv, hi16(tv.z), cx[5]);
            cx[6] = fmaf(qv, lo16(tv.w), cx[6]);
            cx[7] = fmaf(qv, hi16(tv.w), cx[7]);
        }
#pragma unroll
        for (int q = 0; q < 8; ++q) {
            cx[q] += __shfl_xor(cx[q], 16);
            cx[q] += __shfl_xor(cx[q], 32);
        }
        float sA = ((cx[0]+cx[1])+(cx[2]+cx[3])) + ((cx[4]+cx[5])+(cx[6]+cx[7]));
#pragma unroll
        for (int m = 1; m < 16; m <<= 1) sA += __shfl_xor(sA, m);
        cS = sA * (1.f/128.f);
    }
    __syncthreads();   // qw reads done before ctxn overwrites s_X

    // D: verified fold -> ctxn[8][128] (lanes 0-15 of each wave = head wv)
    if (lane < 16) {
        int c = lane, w = wv;
        float den = s_den[w], p0a = s_p0[w], sP = den - p0a, inv = 1.f/den;
#pragma unroll
        for (int q = 0; q < 2; ++q) {
            int j0 = c*8 + q*4;
            float4 lq = *(const float4*)&s_lnq[j0];
            float4 lw = *(const float4*)&ln1_w[j0];
            float4 lb = *(const float4*)&ln1_b[j0];
            float4 o0;
            o0.x = (p0a*lq.x + lw.x*(cx[q*4+0]-cS) + lb.x*sP) * inv;
            o0.y = (p0a*lq.y + lw.y*(cx[q*4+1]-cS) + lb.y*sP) * inv;
            o0.z = (p0a*lq.z + lw.z*(cx[q*4+2]-cS) + lb.z*sP) * inv;
            o0.w = (p0a*lq.w + lw.w*(cx[q*4+3]-cS) + lb.w*sP) * inv;
            *(float4*)&s_X[w*128 + j0] = o0;
        }
    }
    __syncthreads();

    // O: o = Wv @ ctxn + bv  (4 threads/output, K-split 32)
    {
        int d = t >> 2, q4 = t & 3;
        int h = d >> 4;
        const float4* w4 = (const float4*)(W_qkv + (size_t)(2*Dn + d)*Dn) + q4*8;
        const float4* c4 = (const float4*)&s_X[h*128] + q4*8;
        float acc = 0.f;
#pragma unroll
        for (int j = 0; j < 8; ++j) {
            float4 a = w4[j], v = c4[j];
            acc += a.x*v.x + a.y*v.y + a.z*v.z + a.w*v.w;
        }
        acc += __shfl_xor(acc, 1);
        acc += __shfl_xor(acc, 2);
        if (q4 == 0)
            o_ws[(size_t)b*Dn + d] = acc + b_qkv[2*Dn + d];
    }
}

//======================= Kernel C: MLP tail (8 batches/block) =============
__global__ __launch_bounds__(256, 2)
void k_tail(const float* __restrict__ q_in, const float* __restrict__ o_ws,
            const float* __restrict__ W_out, const float* __restrict__ b_out,
            const float* __restrict__ ln2_w, const float* __restrict__ ln2_b,
            const float* __restrict__ ln3_w, const float* __restrict__ ln3_b,
            const float* __restrict__ W_ff1, const float* __restrict__ b_ff1,
            const float* __restrict__ ln4_w, const float* __restrict__ ln4_b,
            const float* __restrict__ W_ff2, const float* __restrict__ b_ff2,
            const float* __restrict__ ln5_w, const float* __restrict__ ln5_b,
            const float* __restrict__ W_head, const float* __restrict__ b_head,
            float* __restrict__ out)
{
    const int t    = threadIdx.x;
    const int lane = t & 63;
    const int wv   = t >> 6;
    const int b0   = blockIdx.x * GC;

    __shared__ __align__(16) float s_qi[GC][Dn];
    __shared__ __align__(16) float s_o [GC][Dn];   // o; later h2
    __shared__ __align__(16) float s_t1[GC][Dn];   // t1; later f2h
    __shared__ __align__(16) float s_h [GC][Dn];
    __shared__ __align__(16) float s_l3[GC][Dn];
    __shared__ __align__(16) float s_f1[GC * DFF];

    ((float4*)&s_qi[0][0])[t] = ((const float4*)(q_in + (size_t)b0*Dn))[t];
    ((float4*)&s_o [0][0])[t] = ((const float4*)(o_ws + (size_t)b0*Dn))[t];
    __syncthreads();

    // P6a: t1 = o @ W_out^T + b_out
    {
        int d = t & 127, grp = t >> 7;
        const float4* w4 = (const float4*)(W_out + (size_t)d * Dn);
        float acc[4] = {0,0,0,0};
#pragma unroll 8
        for (int j = 0; j < 32; ++j) {
            float4 a = w4[j];
#pragma unroll
            for (int gg = 0; gg < 4; ++gg) {
                float4 v = *(const float4*)&s_o[grp*4 + gg][j*4];
                acc[gg] = fmaf(a.x,v.x,acc[gg]); acc[gg] = fmaf(a.y,v.y,acc[gg]);
                acc[gg] = fmaf(a.z,v.z,acc[gg]); acc[gg] = fmaf(a.w,v.w,acc[gg]);
            }
        }
#pragma unroll
        for (int gg = 0; gg < 4; ++gg) s_t1[grp*4 + gg][d] = acc[gg] + b_out[d];
    }
    __syncthreads();

    // P6b: h = LN(t1, ln2) + q_in  (wave wv handles batches wv and wv+4)
    ln_row64<Dn>(&s_t1[wv][0], &s_h[wv][0], ln2_w, ln2_b, &s_qi[wv][0], lane);
    ln_row64<Dn>(&s_t1[wv+4][0], &s_h[wv+4][0], ln2_w, ln2_b, &s_qi[wv+4][0], lane);
    __syncthreads();
    // P6c: ln3h
    ln_row64<Dn>(&s_h[wv][0], &s_l3[wv][0], ln3_w, ln3_b, nullptr, lane);
    ln_row64<Dn>(&s_h[wv+4][0], &s_l3[wv+4][0], ln3_w, ln3_b, nullptr, lane);
    __syncthreads();

    // P6d: f1 = gelu(ln3h @ W_ff1^T + b_ff1)
    {
        int e0 = t, e1 = t + 256;
        const float4* wa = (const float4*)(W_ff1 + (size_t)e0 * Dn);
        const float4* wb = (const float4*)(W_ff1 + (size_t)e1 * Dn);
        float acc0[GC], acc1[GC];
#pragma unroll
        for (int g = 0; g < GC; ++g) { acc0[g] = 0.f; acc1[g] = 0.f; }
#pragma unroll 2
        for (int j = 0; j < 32; ++j) {
            float4 a = wa[j], bb = wb[j];
#pragma unroll
            for (int g = 0; g < GC; ++g) {
                float4 v = *(const float4*)&s_l3[g][j*4];
                acc0[g] = fmaf(a.x,v.x,acc0[g]);  acc0[g] = fmaf(a.y,v.y,acc0[g]);
                acc0[g] = fmaf(a.z,v.z,acc0[g]);  acc0[g] = fmaf(a.w,v.w,acc0[g]);
                acc1[g] = fmaf(bb.x,v.x,acc1[g]); acc1[g] = fmaf(bb.y,v.y,acc1[g]);
                acc1[g] = fmaf(bb.z,v.z,acc1[g]); acc1[g] = fmaf(bb.w,v.w,acc1[g]);
            }
        }
#pragma unroll
        for (int g = 0; g < GC; ++g) {
            float v0 = acc0[g] + b_ff1[e0];
            float v1 = acc1[g] + b_ff1[e1];
            s_f1[g*DFF + e0] = 0.5f * v0 * (1.f + erff(v0 * INV_SQRT2));
            s_f1[g*DFF + e1] = 0.5f * v1 * (1.f + erff(v1 * INV_SQRT2));
        }
    }
    __syncthreads();

    // P6e: LN(f1, ln4) in place
    ln_row64<DFF>(&s_f1[wv*DFF], &s_f1[wv*DFF], ln4_w, ln4_b, nullptr, lane);
    ln_row64<DFF>(&s_f1[(wv+4)*DFF], &s_f1[(wv+4)*DFF], ln4_w, ln4_b, nullptr, lane);
    __syncthreads();

    // P6f: f2h = f1 @ W_ff2^T + b_ff2 + h -> s_t1 (dead)
    {
        int d = t & 127, grp = t >> 7;
        const float4* w4 = (const float4*)(W_ff2 + (size_t)d * DFF);
        float acc[4] = {0,0,0,0};
#pragma unroll 4
        for (int j = 0; j < DFF/4; ++j) {
            float4 a = w4[j];
#pragma unroll
            for (int gg = 0; gg < 4; ++gg) {
                float4 v = ((const float4*)&s_f1[(grp*4 + gg)*DFF])[j];
                acc[gg] = fmaf(a.x,v.x,acc[gg]); acc[gg] = fmaf(a.y,v.y,acc[gg]);
                acc[gg] = fmaf(a.z,v.z,acc[gg]); acc[gg] = fmaf(a.w,v.w,acc[gg]);
            }
        }
#pragma unroll
        for (int gg = 0; gg < 4; ++gg)
            s_t1[grp*4 + gg][d] = acc[gg] + b_ff2[d] + s_h[grp*4 + gg][d];
    }
    __syncthreads();

    // P6g: h2 = LN(ln5) -> s_o (dead)
    ln_row64<Dn>(&s_t1[wv][0], &s_o[wv][0], ln5_w, ln5_b, nullptr, lane);
    ln_row64<Dn>(&s_t1[wv+4][0], &s_o[wv+4][0], ln5_w, ln5_b, nullptr, lane);
    __syncthreads();

    // P6h: out = h2 @ W_head^T + b_head
    {
        int e0 = t, e1 = t + 256;
        const float4* wa = (const float4*)(W_head + (size_t)e0 * Dn);
        const float4* wb = (const float4*)(W_head + (size_t)e1 * Dn);
        float acc0[GC], acc1[GC];
#pragma unroll
        for (int g = 0; g < GC; ++g) { acc0[g] = 0.f; acc1[g] = 0.f; }
#pragma unroll 2
        for (int j = 0; j < 32; ++j) {
            float4 a = wa[j], bb = wb[j];
#pragma unroll
            for (int g = 0; g < GC; ++g) {
                float4 v = *(const float4*)&s_o[g][j*4];
                acc0[g] = fmaf(a.x,v.x,acc0[g]);  acc0[g] = fmaf(a.y,v.y,acc0[g]);
                acc0[g] = fmaf(a.z,v.z,acc0[g]);  acc0[g] = fmaf(a.w,v.w,acc0[g]);
                acc1[g] = fmaf(bb.x,v.x,acc1[g]); acc1[g] = fmaf(bb.y,v.y,acc1[g]);
                acc1[g] = fmaf(bb.z,v.z,acc1[g]); acc1[g] = fmaf(bb.w,v.w,acc1[g]);
            }
        }
#pragma unroll
        for (int g = 0; g < GC; ++g) {
            out[(size_t)(b0+g)*DIN + e0] = acc0[g] + b_head[e0];
            out[(size_t)(b0+g)*DIN + e1] = acc1[g] + b_head[e1];
        }
    }
}

} // namespace

extern "C" void kernel_launch(void* const* d_in, const int* in_sizes, int n_in,
                              void* d_out, int out_size, void* d_ws, size_t ws_size,
                              hipStream_t stream)
{
    const float* x      = (const float*)d_in[0];
    const float* W_in   = (const float*)d_in[1];
    const float* b_in   = (const float*)d_in[2];
    const float* pos    = (const float*)d_in[3];
    const float* mask   = (const float*)d_in[4];
    const float* mem    = (const float*)d_in[5];
    const float* ln1_w  = (const float*)d_in[6];
    const float* ln1_b  = (const float*)d_in[7];
    const float* W_qkv  = (const float*)d_in[8];
    const float* b_qkv  = (const float*)d_in[9];
    const float* W_out  = (const float*)d_in[10];
    const float* b_out  = (const float*)d_in[11];
    const float* ln2_w  = (const float*)d_in[12];
    const float* ln2_b  = (const float*)d_in[13];
    const float* ln3_w  = (const float*)d_in[14];
    const float* ln3_b  = (const float*)d_in[15];
    const float* W_ff1  = (const float*)d_in[16];
    const float* b_ff1  = (const float*)d_in[17];
    const float* ln4_w  = (const float*)d_in[18];
    const float* ln4_b  = (const float*)d_in[19];
    const float* W_ff2  = (const float*)d_in[20];
    const float* b_ff2  = (const float*)d_in[21];
    const float* ln5_w  = (const float*)d_in[22];
    const float* ln5_b  = (const float*)d_in[23];
    const float* W_head = (const float*)d_in[24];
    const float* b_head = (const float*)d_in[25];

    const int B = in_sizes[0] / DIN;   // 4096
    float* ws_qin = (float*)d_ws;                       // B*128 floats (2 MB)
    float* ws_o   = (float*)d_ws + (size_t)B * Dn;      // B*128 floats (2 MB)

    k_qin<<<dim3(B / 8), dim3(256), 0, stream>>>(x, W_in, b_in, pos, ws_qin);
    k_attn<<<dim3(B), dim3(512), 0, stream>>>(ws_qin, mask, mem,
                                              ln1_w, ln1_b, W_qkv, b_qkv, ws_o);
    k_tail<<<dim3(B / GC), dim3(256), 0, stream>>>(ws_qin, ws_o,
        W_out, b_out, ln2_w, ln2_b, ln3_w, ln3_b,
        W_ff1, b_ff1, ln4_w, ln4_b, W_ff2, b_ff2,
        ln5_w, ln5_b, W_head, b_head, (float*)d_out);
}